// Round 1
// baseline (451.128 us; speedup 1.0000x reference)
//
#include <hip/hip_runtime.h>
#include <math.h>

// Problem constants
#define NB   16      // batches
#define NN   512     // nodes per batch
#define FIN  256
#define HID  128
#define FOUT 256
#define TOPK 16
#define ROWS (NB*NN) // 8192
#define LN_EPS 1e-5f

// ---------------------------------------------------------------------------
// K1: fused projection GEMM  Y[8192, 512] = X[8192,256] @ [Wq|Wk|Wv|Wr] + bias
// Y cols 0:128=q, 128:256=k, 256:384=v, 384:512=r
// ---------------------------------------------------------------------------
__global__ __launch_bounds__(256) void k_proj(
    const float* __restrict__ X,
    const float* __restrict__ Wq, const float* __restrict__ bq,
    const float* __restrict__ Wk, const float* __restrict__ bk,
    const float* __restrict__ Wv, const float* __restrict__ bv,
    const float* __restrict__ Wr, const float* __restrict__ br,
    float* __restrict__ Y)
{
    const int bc0 = blockIdx.x * 64;   // col tile (0..448)
    const int br0 = blockIdx.y * 64;   // row tile
    const int widx = bc0 >> 7;
    const float* W; const float* bias;
    if      (widx == 0) { W = Wq; bias = bq; }
    else if (widx == 1) { W = Wk; bias = bk; }
    else if (widx == 2) { W = Wv; bias = bv; }
    else                { W = Wr; bias = br; }
    const int wc0 = bc0 & 127;

    __shared__ float As[64][33];
    __shared__ float Bs[32][65];

    const int tid = threadIdx.x;
    const int tx = tid & 15, ty = tid >> 4;
    float acc[4][4] = {};

    for (int k0 = 0; k0 < 256; k0 += 32) {
        {
            const int r = tid >> 5, kk = tid & 31;
            #pragma unroll
            for (int i = 0; i < 8; i++)
                As[r + i*8][kk] = X[(size_t)(br0 + r + i*8) * FIN + k0 + kk];
        }
        {
            const int kk = tid >> 6, c = tid & 63;
            #pragma unroll
            for (int i = 0; i < 8; i++)
                Bs[kk + i*4][c] = W[(size_t)(k0 + kk + i*4) * HID + wc0 + c];
        }
        __syncthreads();
        #pragma unroll
        for (int kk = 0; kk < 32; kk++) {
            float a[4], b[4];
            #pragma unroll
            for (int i = 0; i < 4; i++) a[i] = As[ty*4+i][kk];
            #pragma unroll
            for (int j = 0; j < 4; j++) b[j] = Bs[kk][tx*4+j];
            #pragma unroll
            for (int i = 0; i < 4; i++)
                #pragma unroll
                for (int j = 0; j < 4; j++)
                    acc[i][j] += a[i] * b[j];
        }
        __syncthreads();
    }
    #pragma unroll
    for (int i = 0; i < 4; i++) {
        const int r = br0 + ty*4 + i;
        #pragma unroll
        for (int j = 0; j < 4; j++) {
            const int c = tx*4 + j;
            Y[(size_t)r*512 + bc0 + c] = acc[i][j] + bias[wc0 + c];
        }
    }
}

// ---------------------------------------------------------------------------
// K2: attention scores  S[b,n,m] = (q_n . k_m) / sqrt(HID)
// ---------------------------------------------------------------------------
__global__ __launch_bounds__(256) void k_scores(
    const float* __restrict__ Y, float* __restrict__ S)
{
    const int b  = blockIdx.z;
    const int m0 = blockIdx.x * 64;
    const int n0 = blockIdx.y * 64;
    const float scale = 0.08838834764831845f;  // 1/sqrt(128)

    __shared__ float As[64][33];   // q rows  [row][k]
    __shared__ float Bs[64][33];   // k rows  [row][k]

    const int tid = threadIdx.x;
    const int tx = tid & 15, ty = tid >> 4;
    float acc[4][4] = {};

    const float* Yb = Y + (size_t)b * NN * 512;
    for (int k0 = 0; k0 < HID; k0 += 32) {
        const int r = tid >> 5, kk = tid & 31;
        #pragma unroll
        for (int i = 0; i < 8; i++)
            As[r + i*8][kk] = Yb[(size_t)(n0 + r + i*8)*512 + 0   + k0 + kk];
        #pragma unroll
        for (int i = 0; i < 8; i++)
            Bs[r + i*8][kk] = Yb[(size_t)(m0 + r + i*8)*512 + 128 + k0 + kk];
        __syncthreads();
        #pragma unroll
        for (int kk = 0; kk < 32; kk++) {
            float a[4], bb[4];
            #pragma unroll
            for (int i = 0; i < 4; i++) a[i]  = As[ty*4+i][kk];
            #pragma unroll
            for (int j = 0; j < 4; j++) bb[j] = Bs[tx*4+j][kk];
            #pragma unroll
            for (int i = 0; i < 4; i++)
                #pragma unroll
                for (int j = 0; j < 4; j++)
                    acc[i][j] += a[i] * bb[j];
        }
        __syncthreads();
    }
    float* Sb = S + (size_t)b * NN * NN;
    #pragma unroll
    for (int i = 0; i < 4; i++)
        #pragma unroll
        for (int j = 0; j < 4; j++)
            Sb[(size_t)(n0 + ty*4 + i)*NN + m0 + tx*4 + j] = acc[i][j] * scale;
}

// ---------------------------------------------------------------------------
// K3: row softmax over 512 (in place)
// ---------------------------------------------------------------------------
__global__ __launch_bounds__(256) void k_softmax(float* __restrict__ S)
{
    float* p = S + (size_t)blockIdx.x * NN;
    const int tid = threadIdx.x;
    const int lane = tid & 63, wave = tid >> 6;
    __shared__ float red[4];

    float v0 = p[tid], v1 = p[tid + 256];
    float mx = fmaxf(v0, v1);
    #pragma unroll
    for (int off = 32; off > 0; off >>= 1) mx = fmaxf(mx, __shfl_down(mx, off));
    if (lane == 0) red[wave] = mx;
    __syncthreads();
    mx = fmaxf(fmaxf(red[0], red[1]), fmaxf(red[2], red[3]));
    __syncthreads();

    float e0 = __expf(v0 - mx), e1 = __expf(v1 - mx);
    float s = e0 + e1;
    #pragma unroll
    for (int off = 32; off > 0; off >>= 1) s += __shfl_down(s, off);
    if (lane == 0) red[wave] = s;
    __syncthreads();
    s = red[0] + red[1] + red[2] + red[3];
    const float inv = 1.0f / s;
    p[tid] = e0 * inv;
    p[tid + 256] = e1 * inv;
}

// ---------------------------------------------------------------------------
// K4: h = P @ V + R   (per batch: 512x512 @ 512x128)
// ---------------------------------------------------------------------------
__global__ __launch_bounds__(256) void k_hgemm(
    const float* __restrict__ S, const float* __restrict__ Y,
    float* __restrict__ H)
{
    const int b  = blockIdx.z;
    const int c0 = blockIdx.x * 64;   // 0 or 64
    const int n0 = blockIdx.y * 64;

    __shared__ float As[64][33];
    __shared__ float Bs[32][65];

    const int tid = threadIdx.x;
    const int tx = tid & 15, ty = tid >> 4;
    float acc[4][4] = {};

    const float* P = S + (size_t)b * NN * NN;
    for (int k0 = 0; k0 < NN; k0 += 32) {
        {
            const int r = tid >> 5, kk = tid & 31;
            #pragma unroll
            for (int i = 0; i < 8; i++)
                As[r + i*8][kk] = P[(size_t)(n0 + r + i*8)*NN + k0 + kk];
        }
        {
            const int kk = tid >> 6, c = tid & 63;
            #pragma unroll
            for (int i = 0; i < 8; i++)
                Bs[kk + i*4][c] = Y[(size_t)(b*NN + k0 + kk + i*4)*512 + 256 + c0 + c];
        }
        __syncthreads();
        #pragma unroll
        for (int kk = 0; kk < 32; kk++) {
            float a[4], bb[4];
            #pragma unroll
            for (int i = 0; i < 4; i++) a[i]  = As[ty*4+i][kk];
            #pragma unroll
            for (int j = 0; j < 4; j++) bb[j] = Bs[kk][tx*4+j];
            #pragma unroll
            for (int i = 0; i < 4; i++)
                #pragma unroll
                for (int j = 0; j < 4; j++)
                    acc[i][j] += a[i] * bb[j];
        }
        __syncthreads();
    }
    #pragma unroll
    for (int i = 0; i < 4; i++) {
        const int gr = b*NN + n0 + ty*4 + i;
        #pragma unroll
        for (int j = 0; j < 4; j++) {
            const int c = c0 + tx*4 + j;
            H[(size_t)gr*HID + c] = acc[i][j] + Y[(size_t)gr*512 + 384 + c];
        }
    }
}

// ---------------------------------------------------------------------------
// K5: per-row squared norm of h
// ---------------------------------------------------------------------------
__global__ __launch_bounds__(256) void k_sq(
    const float* __restrict__ H, float* __restrict__ SQ)
{
    const int row = blockIdx.x * 4 + (threadIdx.x >> 6);
    const int lane = threadIdx.x & 63;
    float a = H[(size_t)row*HID + lane];
    float c = H[(size_t)row*HID + 64 + lane];
    float s = a*a + c*c;
    #pragma unroll
    for (int off = 32; off > 0; off >>= 1) s += __shfl_down(s, off);
    if (lane == 0) SQ[row] = s;
}

// ---------------------------------------------------------------------------
// K6: AB[8192,512]: cols 0:256 = a = h@(Wc_top - Wc_bot) + bc
//                   cols 256:512 = b = h@Wc_bot
// ---------------------------------------------------------------------------
__global__ __launch_bounds__(256) void k_ab(
    const float* __restrict__ H, const float* __restrict__ Wc,
    const float* __restrict__ bc, float* __restrict__ AB)
{
    const int bc0 = blockIdx.x * 64;    // 0..448
    const int br0 = blockIdx.y * 64;
    const bool bhalf = bc0 >= 256;
    const int c0 = bhalf ? bc0 - 256 : bc0;

    __shared__ float As[64][33];
    __shared__ float Bs[32][65];

    const int tid = threadIdx.x;
    const int tx = tid & 15, ty = tid >> 4;
    float acc[4][4] = {};

    for (int k0 = 0; k0 < HID; k0 += 32) {
        {
            const int r = tid >> 5, kk = tid & 31;
            #pragma unroll
            for (int i = 0; i < 8; i++)
                As[r + i*8][kk] = H[(size_t)(br0 + r + i*8)*HID + k0 + kk];
        }
        {
            const int kk = tid >> 6, c = tid & 63;
            #pragma unroll
            for (int i = 0; i < 8; i++) {
                const int k = k0 + kk + i*4;
                const float wbot = Wc[(size_t)(HID + k)*FOUT + c0 + c];
                Bs[kk + i*4][c] = bhalf ? wbot
                                        : (Wc[(size_t)k*FOUT + c0 + c] - wbot);
            }
        }
        __syncthreads();
        #pragma unroll
        for (int kk = 0; kk < 32; kk++) {
            float a[4], bb[4];
            #pragma unroll
            for (int i = 0; i < 4; i++) a[i]  = As[ty*4+i][kk];
            #pragma unroll
            for (int j = 0; j < 4; j++) bb[j] = Bs[kk][tx*4+j];
            #pragma unroll
            for (int i = 0; i < 4; i++)
                #pragma unroll
                for (int j = 0; j < 4; j++)
                    acc[i][j] += a[i] * bb[j];
        }
        __syncthreads();
    }
    #pragma unroll
    for (int i = 0; i < 4; i++)
        #pragma unroll
        for (int j = 0; j < 4; j++) {
            const int c = tx*4 + j;
            const float add = bhalf ? 0.0f : bc[c0 + c];
            AB[(size_t)(br0 + ty*4 + i)*512 + bc0 + c] = acc[i][j] + add;
        }
}

// ---------------------------------------------------------------------------
// K7: fused dist + top-16 + gather-max + LayerNorm + SELU
// one block = 16 rows of one batch
// ---------------------------------------------------------------------------
__global__ __launch_bounds__(256) void k_final(
    const float* __restrict__ H, const float* __restrict__ SQ,
    const float* __restrict__ AB,
    const float* __restrict__ ln_scale, const float* __restrict__ ln_bias,
    float* __restrict__ out)
{
    const int b  = blockIdx.x >> 5;          // 32 blocks per batch
    const int n0 = (blockIdx.x & 31) * 16;
    const int gb0 = b * NN;
    const int tid = threadIdx.x;
    const int lane = tid & 63, wave = tid >> 6;

    __shared__ float sHn[16][128];
    __shared__ float sHm[32][128];
    __shared__ float sD[16][512];
    __shared__ int   sIdx[16][TOPK];
    __shared__ float sRed[4];

    // load the block's 16 h rows
    for (int i = tid; i < 16*128; i += 256) {
        const int r = i >> 7, d = i & 127;
        sHn[r][d] = H[(size_t)(gb0 + n0 + r)*HID + d];
    }

    // phase 1: dist[16][512] via tiled dot products
    const int tm = tid & 31;     // m within tile
    const int tn = tid >> 5;     // 0..7 -> rows tn, tn+8
    const float sqn0 = SQ[gb0 + n0 + tn];
    const float sqn1 = SQ[gb0 + n0 + tn + 8];
    for (int m0 = 0; m0 < NN; m0 += 32) {
        __syncthreads();
        for (int i = tid; i < 32*128; i += 256) {
            const int r = i >> 7, d = i & 127;
            sHm[r][d] = H[(size_t)(gb0 + m0 + r)*HID + d];
        }
        __syncthreads();
        float dot0 = 0.f, dot1 = 0.f;
        #pragma unroll 8
        for (int d = 0; d < 128; d++) {
            const float hm = sHm[tm][d];
            dot0 += sHn[tn][d]     * hm;
            dot1 += sHn[tn + 8][d] * hm;
        }
        const float sqm = SQ[gb0 + m0 + tm];
        sD[tn][m0 + tm]     = sqn0 + sqm - 2.0f * dot0;
        sD[tn + 8][m0 + tm] = sqn1 + sqm - 2.0f * dot1;
    }
    __syncthreads();

    // phase 2: per-row top-16 smallest (tie -> lower index), wave per row
    for (int rr = 0; rr < 4; rr++) {
        const int row = wave * 4 + rr;
        for (int it = 0; it < TOPK; it++) {
            float bestv = INFINITY; int besti = 0x7fffffff;
            #pragma unroll
            for (int j = 0; j < 8; j++) {
                const int m = j*64 + lane;
                const float v = sD[row][m];
                if (v < bestv) { bestv = v; besti = m; }
            }
            #pragma unroll
            for (int off = 1; off < 64; off <<= 1) {
                const float ov = __shfl_xor(bestv, off);
                const int   oi = __shfl_xor(besti, off);
                if (ov < bestv || (ov == bestv && oi < besti)) { bestv = ov; besti = oi; }
            }
            if (lane == 0) sIdx[row][it] = besti;
            if ((besti & 63) == lane) sD[row][besti] = INFINITY;  // remove
        }
    }
    __syncthreads();

    // phase 3: gather-max + LayerNorm + SELU; thread = output channel
    const int o = tid;
    const float lsc = ln_scale[o], lbi = ln_bias[o];
    for (int r = 0; r < 16; r++) {
        const int gr = gb0 + n0 + r;
        const float a = AB[(size_t)gr*512 + o];
        float bmax = -INFINITY;
        #pragma unroll
        for (int k2 = 0; k2 < TOPK; k2++) {
            const int m = sIdx[r][k2];
            bmax = fmaxf(bmax, AB[(size_t)(gb0 + m)*512 + 256 + o]);
        }
        const float y = a + bmax;

        float s = y;
        #pragma unroll
        for (int off = 32; off > 0; off >>= 1) s += __shfl_down(s, off);
        if (lane == 0) sRed[wave] = s;
        __syncthreads();
        const float mu = (sRed[0] + sRed[1] + sRed[2] + sRed[3]) * (1.0f/256.0f);
        __syncthreads();

        const float d = y - mu;
        float s2 = d * d;
        #pragma unroll
        for (int off = 32; off > 0; off >>= 1) s2 += __shfl_down(s2, off);
        if (lane == 0) sRed[wave] = s2;
        __syncthreads();
        const float var = (sRed[0] + sRed[1] + sRed[2] + sRed[3]) * (1.0f/256.0f);
        __syncthreads();

        const float z = d * rsqrtf(var + LN_EPS) * lsc + lbi;
        const float lam = 1.0507009873554805f, alpha = 1.6732632423543772f;
        const float res = z > 0.0f ? lam * z : lam * alpha * expm1f(z);
        out[(size_t)gr*FOUT + o] = res;
    }
}

// ---------------------------------------------------------------------------
extern "C" void kernel_launch(void* const* d_in, const int* in_sizes, int n_in,
                              void* d_out, int out_size, void* d_ws, size_t ws_size,
                              hipStream_t stream)
{
    (void)in_sizes; (void)n_in; (void)out_size; (void)ws_size;
    const float* X   = (const float*)d_in[0];
    const float* Wq  = (const float*)d_in[2];
    const float* bq  = (const float*)d_in[3];
    const float* Wk  = (const float*)d_in[4];
    const float* bk  = (const float*)d_in[5];
    const float* Wv  = (const float*)d_in[6];
    const float* bv  = (const float*)d_in[7];
    const float* Wr  = (const float*)d_in[8];
    const float* br  = (const float*)d_in[9];
    const float* Wc  = (const float*)d_in[10];
    const float* bc  = (const float*)d_in[11];
    const float* lns = (const float*)d_in[12];
    const float* lnb = (const float*)d_in[13];
    float* out = (float*)d_out;

    float* ws = (float*)d_ws;
    float* Y  = ws;                              // 8192*512
    float* S  = Y + (size_t)ROWS*512;            // 16*512*512
    float* H  = S + (size_t)NB*NN*NN;            // 8192*128
    float* SQ = H + (size_t)ROWS*HID;            // 8192
    float* AB = SQ + ROWS;                       // 8192*512

    k_proj   <<<dim3(8,128),  256, 0, stream>>>(X, Wq,bq, Wk,bk, Wv,bv, Wr,br, Y);
    k_scores <<<dim3(8,8,16), 256, 0, stream>>>(Y, S);
    k_softmax<<<ROWS,         256, 0, stream>>>(S);
    k_hgemm  <<<dim3(2,8,16), 256, 0, stream>>>(S, Y, H);
    k_sq     <<<ROWS/4,       256, 0, stream>>>(H, SQ);
    k_ab     <<<dim3(8,128),  256, 0, stream>>>(H, Wc, bc, AB);
    k_final  <<<NB*NN/16,     256, 0, stream>>>(H, SQ, AB, lns, lnb, out);
}

// Round 2
// 287.444 us; speedup vs baseline: 1.5694x; 1.5694x over previous
//
#include <hip/hip_runtime.h>
#include <math.h>

// Problem constants
#define NB   16      // batches
#define NN   512     // nodes per batch
#define FIN  256
#define HID  128
#define FOUT 256
#define TOPK 16
#define ROWS (NB*NN) // 8192
#define LN_EPS 1e-5f

// ---------------------------------------------------------------------------
// K1: fused projection GEMM  Y[8192, 512] = X[8192,256] @ [Wq|Wk|Wv|Wr] + bias
// Y cols 0:128=q, 128:256=k, 256:384=v, 384:512=r
// ---------------------------------------------------------------------------
__global__ __launch_bounds__(256) void k_proj(
    const float* __restrict__ X,
    const float* __restrict__ Wq, const float* __restrict__ bq,
    const float* __restrict__ Wk, const float* __restrict__ bk,
    const float* __restrict__ Wv, const float* __restrict__ bv,
    const float* __restrict__ Wr, const float* __restrict__ br,
    float* __restrict__ Y)
{
    const int bc0 = blockIdx.x * 64;   // col tile (0..448)
    const int br0 = blockIdx.y * 64;   // row tile
    const int widx = bc0 >> 7;
    const float* W; const float* bias;
    if      (widx == 0) { W = Wq; bias = bq; }
    else if (widx == 1) { W = Wk; bias = bk; }
    else if (widx == 2) { W = Wv; bias = bv; }
    else                { W = Wr; bias = br; }
    const int wc0 = bc0 & 127;

    __shared__ float As[64][33];
    __shared__ float Bs[32][65];

    const int tid = threadIdx.x;
    const int tx = tid & 15, ty = tid >> 4;
    float acc[4][4] = {};

    for (int k0 = 0; k0 < 256; k0 += 32) {
        {
            const int r = tid >> 5, kk = tid & 31;
            #pragma unroll
            for (int i = 0; i < 8; i++)
                As[r + i*8][kk] = X[(size_t)(br0 + r + i*8) * FIN + k0 + kk];
        }
        {
            const int kk = tid >> 6, c = tid & 63;
            #pragma unroll
            for (int i = 0; i < 8; i++)
                Bs[kk + i*4][c] = W[(size_t)(k0 + kk + i*4) * HID + wc0 + c];
        }
        __syncthreads();
        #pragma unroll
        for (int kk = 0; kk < 32; kk++) {
            float a[4], b[4];
            #pragma unroll
            for (int i = 0; i < 4; i++) a[i] = As[ty*4+i][kk];
            #pragma unroll
            for (int j = 0; j < 4; j++) b[j] = Bs[kk][tx*4+j];
            #pragma unroll
            for (int i = 0; i < 4; i++)
                #pragma unroll
                for (int j = 0; j < 4; j++)
                    acc[i][j] += a[i] * b[j];
        }
        __syncthreads();
    }
    #pragma unroll
    for (int i = 0; i < 4; i++) {
        const int r = br0 + ty*4 + i;
        #pragma unroll
        for (int j = 0; j < 4; j++) {
            const int c = tx*4 + j;
            Y[(size_t)r*512 + bc0 + c] = acc[i][j] + bias[wc0 + c];
        }
    }
}

// ---------------------------------------------------------------------------
// K2: attention scores  S[b,n,m] = (q_n . k_m) / sqrt(HID)
// ---------------------------------------------------------------------------
__global__ __launch_bounds__(256) void k_scores(
    const float* __restrict__ Y, float* __restrict__ S)
{
    const int b  = blockIdx.z;
    const int m0 = blockIdx.x * 64;
    const int n0 = blockIdx.y * 64;
    const float scale = 0.08838834764831845f;  // 1/sqrt(128)

    __shared__ float As[64][33];   // q rows  [row][k]
    __shared__ float Bs[64][33];   // k rows  [row][k]

    const int tid = threadIdx.x;
    const int tx = tid & 15, ty = tid >> 4;
    float acc[4][4] = {};

    const float* Yb = Y + (size_t)b * NN * 512;
    for (int k0 = 0; k0 < HID; k0 += 32) {
        const int r = tid >> 5, kk = tid & 31;
        #pragma unroll
        for (int i = 0; i < 8; i++)
            As[r + i*8][kk] = Yb[(size_t)(n0 + r + i*8)*512 + 0   + k0 + kk];
        #pragma unroll
        for (int i = 0; i < 8; i++)
            Bs[r + i*8][kk] = Yb[(size_t)(m0 + r + i*8)*512 + 128 + k0 + kk];
        __syncthreads();
        #pragma unroll
        for (int kk = 0; kk < 32; kk++) {
            float a[4], bb[4];
            #pragma unroll
            for (int i = 0; i < 4; i++) a[i]  = As[ty*4+i][kk];
            #pragma unroll
            for (int j = 0; j < 4; j++) bb[j] = Bs[tx*4+j][kk];
            #pragma unroll
            for (int i = 0; i < 4; i++)
                #pragma unroll
                for (int j = 0; j < 4; j++)
                    acc[i][j] += a[i] * bb[j];
        }
        __syncthreads();
    }
    float* Sb = S + (size_t)b * NN * NN;
    #pragma unroll
    for (int i = 0; i < 4; i++)
        #pragma unroll
        for (int j = 0; j < 4; j++)
            Sb[(size_t)(n0 + ty*4 + i)*NN + m0 + tx*4 + j] = acc[i][j] * scale;
}

// ---------------------------------------------------------------------------
// K3: row softmax over 512 (in place)
// ---------------------------------------------------------------------------
__global__ __launch_bounds__(256) void k_softmax(float* __restrict__ S)
{
    float* p = S + (size_t)blockIdx.x * NN;
    const int tid = threadIdx.x;
    const int lane = tid & 63, wave = tid >> 6;
    __shared__ float red[4];

    float v0 = p[tid], v1 = p[tid + 256];
    float mx = fmaxf(v0, v1);
    #pragma unroll
    for (int off = 32; off > 0; off >>= 1) mx = fmaxf(mx, __shfl_down(mx, off));
    if (lane == 0) red[wave] = mx;
    __syncthreads();
    mx = fmaxf(fmaxf(red[0], red[1]), fmaxf(red[2], red[3]));
    __syncthreads();

    float e0 = __expf(v0 - mx), e1 = __expf(v1 - mx);
    float s = e0 + e1;
    #pragma unroll
    for (int off = 32; off > 0; off >>= 1) s += __shfl_down(s, off);
    if (lane == 0) red[wave] = s;
    __syncthreads();
    s = red[0] + red[1] + red[2] + red[3];
    const float inv = 1.0f / s;
    p[tid] = e0 * inv;
    p[tid + 256] = e1 * inv;
}

// ---------------------------------------------------------------------------
// K4: h = P @ V + R   (per batch: 512x512 @ 512x128)
// ---------------------------------------------------------------------------
__global__ __launch_bounds__(256) void k_hgemm(
    const float* __restrict__ S, const float* __restrict__ Y,
    float* __restrict__ H)
{
    const int b  = blockIdx.z;
    const int c0 = blockIdx.x * 64;   // 0 or 64
    const int n0 = blockIdx.y * 64;

    __shared__ float As[64][33];
    __shared__ float Bs[32][65];

    const int tid = threadIdx.x;
    const int tx = tid & 15, ty = tid >> 4;
    float acc[4][4] = {};

    const float* P = S + (size_t)b * NN * NN;
    for (int k0 = 0; k0 < NN; k0 += 32) {
        {
            const int r = tid >> 5, kk = tid & 31;
            #pragma unroll
            for (int i = 0; i < 8; i++)
                As[r + i*8][kk] = P[(size_t)(n0 + r + i*8)*NN + k0 + kk];
        }
        {
            const int kk = tid >> 6, c = tid & 63;
            #pragma unroll
            for (int i = 0; i < 8; i++)
                Bs[kk + i*4][c] = Y[(size_t)(b*NN + k0 + kk + i*4)*512 + 256 + c0 + c];
        }
        __syncthreads();
        #pragma unroll
        for (int kk = 0; kk < 32; kk++) {
            float a[4], bb[4];
            #pragma unroll
            for (int i = 0; i < 4; i++) a[i]  = As[ty*4+i][kk];
            #pragma unroll
            for (int j = 0; j < 4; j++) bb[j] = Bs[kk][tx*4+j];
            #pragma unroll
            for (int i = 0; i < 4; i++)
                #pragma unroll
                for (int j = 0; j < 4; j++)
                    acc[i][j] += a[i] * bb[j];
        }
        __syncthreads();
    }
    #pragma unroll
    for (int i = 0; i < 4; i++) {
        const int gr = b*NN + n0 + ty*4 + i;
        #pragma unroll
        for (int j = 0; j < 4; j++) {
            const int c = c0 + tx*4 + j;
            H[(size_t)gr*HID + c] = acc[i][j] + Y[(size_t)gr*512 + 384 + c];
        }
    }
}

// ---------------------------------------------------------------------------
// K5: per-row squared norm of h
// ---------------------------------------------------------------------------
__global__ __launch_bounds__(256) void k_sq(
    const float* __restrict__ H, float* __restrict__ SQ)
{
    const int row = blockIdx.x * 4 + (threadIdx.x >> 6);
    const int lane = threadIdx.x & 63;
    float a = H[(size_t)row*HID + lane];
    float c = H[(size_t)row*HID + 64 + lane];
    float s = a*a + c*c;
    #pragma unroll
    for (int off = 32; off > 0; off >>= 1) s += __shfl_down(s, off);
    if (lane == 0) SQ[row] = s;
}

// ---------------------------------------------------------------------------
// K6: AB[8192,512]: cols 0:256 = a = h@(Wc_top - Wc_bot) + bc
//                   cols 256:512 = b = h@Wc_bot
// ---------------------------------------------------------------------------
__global__ __launch_bounds__(256) void k_ab(
    const float* __restrict__ H, const float* __restrict__ Wc,
    const float* __restrict__ bc, float* __restrict__ AB)
{
    const int bc0 = blockIdx.x * 64;    // 0..448
    const int br0 = blockIdx.y * 64;
    const bool bhalf = bc0 >= 256;
    const int c0 = bhalf ? bc0 - 256 : bc0;

    __shared__ float As[64][33];
    __shared__ float Bs[32][65];

    const int tid = threadIdx.x;
    const int tx = tid & 15, ty = tid >> 4;
    float acc[4][4] = {};

    for (int k0 = 0; k0 < HID; k0 += 32) {
        {
            const int r = tid >> 5, kk = tid & 31;
            #pragma unroll
            for (int i = 0; i < 8; i++)
                As[r + i*8][kk] = H[(size_t)(br0 + r + i*8)*HID + k0 + kk];
        }
        {
            const int kk = tid >> 6, c = tid & 63;
            #pragma unroll
            for (int i = 0; i < 8; i++) {
                const int k = k0 + kk + i*4;
                const float wbot = Wc[(size_t)(HID + k)*FOUT + c0 + c];
                Bs[kk + i*4][c] = bhalf ? wbot
                                        : (Wc[(size_t)k*FOUT + c0 + c] - wbot);
            }
        }
        __syncthreads();
        #pragma unroll
        for (int kk = 0; kk < 32; kk++) {
            float a[4], bb[4];
            #pragma unroll
            for (int i = 0; i < 4; i++) a[i]  = As[ty*4+i][kk];
            #pragma unroll
            for (int j = 0; j < 4; j++) bb[j] = Bs[kk][tx*4+j];
            #pragma unroll
            for (int i = 0; i < 4; i++)
                #pragma unroll
                for (int j = 0; j < 4; j++)
                    acc[i][j] += a[i] * bb[j];
        }
        __syncthreads();
    }
    #pragma unroll
    for (int i = 0; i < 4; i++)
        #pragma unroll
        for (int j = 0; j < 4; j++) {
            const int c = tx*4 + j;
            const float add = bhalf ? 0.0f : bc[c0 + c];
            AB[(size_t)(br0 + ty*4 + i)*512 + bc0 + c] = acc[i][j] + add;
        }
}

// ---------------------------------------------------------------------------
// K7: pairwise distance GEMM (k_scores structure, conflict-free)
// D[b,n,m] = SQ[n] + SQ[m] - 2 * (h_n . h_m)
// ---------------------------------------------------------------------------
__global__ __launch_bounds__(256) void k_dist(
    const float* __restrict__ H, const float* __restrict__ SQ,
    float* __restrict__ D)
{
    const int b  = blockIdx.z;
    const int m0 = blockIdx.x * 64;
    const int n0 = blockIdx.y * 64;

    __shared__ float As[64][33];   // h rows (n) [row][k]
    __shared__ float Bs[64][33];   // h rows (m) [row][k]

    const int tid = threadIdx.x;
    const int tx = tid & 15, ty = tid >> 4;
    float acc[4][4] = {};

    const float* Hb = H + (size_t)b * NN * HID;
    for (int k0 = 0; k0 < HID; k0 += 32) {
        const int r = tid >> 5, kk = tid & 31;
        #pragma unroll
        for (int i = 0; i < 8; i++)
            As[r + i*8][kk] = Hb[(size_t)(n0 + r + i*8)*HID + k0 + kk];
        #pragma unroll
        for (int i = 0; i < 8; i++)
            Bs[r + i*8][kk] = Hb[(size_t)(m0 + r + i*8)*HID + k0 + kk];
        __syncthreads();
        #pragma unroll
        for (int kk = 0; kk < 32; kk++) {
            float a[4], bb[4];
            #pragma unroll
            for (int i = 0; i < 4; i++) a[i]  = As[ty*4+i][kk];
            #pragma unroll
            for (int j = 0; j < 4; j++) bb[j] = Bs[tx*4+j][kk];
            #pragma unroll
            for (int i = 0; i < 4; i++)
                #pragma unroll
                for (int j = 0; j < 4; j++)
                    acc[i][j] += a[i] * bb[j];
        }
        __syncthreads();
    }
    const int gb0 = b * NN;
    float sqn[4], sqm[4];
    #pragma unroll
    for (int i = 0; i < 4; i++) sqn[i] = SQ[gb0 + n0 + ty*4 + i];
    #pragma unroll
    for (int j = 0; j < 4; j++) sqm[j] = SQ[gb0 + m0 + tx*4 + j];
    float* Db = D + (size_t)b * NN * NN;
    #pragma unroll
    for (int i = 0; i < 4; i++)
        #pragma unroll
        for (int j = 0; j < 4; j++)
            Db[(size_t)(n0 + ty*4 + i)*NN + m0 + tx*4 + j]
                = sqn[i] + sqm[j] - 2.0f * acc[i][j];
}

// ---------------------------------------------------------------------------
// K8: per-row: top-16 (register argmin, wave per row) + gather-max
//     + LayerNorm + SELU.  No LDS, no barriers.
// lane holds channels o = lane + 64*c (c=0..3); dist values m = chunk*256 +
// lane*4 + cc (chunk=0,1; cc=0..3) in 8 registers.
// ---------------------------------------------------------------------------
__global__ __launch_bounds__(256) void k_out(
    const float* __restrict__ D, const float* __restrict__ AB,
    const float* __restrict__ ln_scale, const float* __restrict__ ln_bias,
    float* __restrict__ out)
{
    const int row  = blockIdx.x * 4 + (threadIdx.x >> 6);  // 0..8191
    const int lane = threadIdx.x & 63;
    const int gb0  = row & ~(NN - 1);                      // batch base row

    // load this row's 512 distances into 8 regs
    const float* drow = D + (size_t)row * NN;
    const float4 q0 = ((const float4*)drow)[lane];          // m = 4*lane + cc
    const float4 q1 = ((const float4*)drow)[64 + lane];     // m = 256 + 4*lane + cc
    float v[8] = {q0.x, q0.y, q0.z, q0.w, q1.x, q1.y, q1.z, q1.w};

    // preload ln params + own a-row
    const float lsc0 = ln_scale[lane],       lbi0 = ln_bias[lane];
    const float lsc1 = ln_scale[lane + 64],  lbi1 = ln_bias[lane + 64];
    const float lsc2 = ln_scale[lane + 128], lbi2 = ln_bias[lane + 128];
    const float lsc3 = ln_scale[lane + 192], lbi3 = ln_bias[lane + 192];
    const float* arow = AB + (size_t)row * 512;
    const float a0 = arow[lane], a1 = arow[lane + 64],
                a2 = arow[lane + 128], a3 = arow[lane + 192];

    float bm0 = -INFINITY, bm1 = -INFINITY, bm2 = -INFINITY, bm3 = -INFINITY;

    for (int it = 0; it < TOPK; it++) {
        // local argmin over 8 register values (ascending m => strict < keeps lowest m)
        float bestv = v[0]; int bestm = 4*lane;
        #pragma unroll
        for (int j = 1; j < 8; j++) {
            const int m = (j >> 2)*256 + 4*lane + (j & 3);
            if (v[j] < bestv) { bestv = v[j]; bestm = m; }
        }
        // wave argmin, tie -> lower m
        #pragma unroll
        for (int off = 1; off < 64; off <<= 1) {
            const float ov = __shfl_xor(bestv, off);
            const int   om = __shfl_xor(bestm, off);
            if (ov < bestv || (ov == bestv && om < bestm)) { bestv = ov; bestm = om; }
        }
        // gather neighbor b-row (wave-uniform bestm -> coalesced) and max
        const float* brow = AB + (size_t)(gb0 + bestm) * 512 + 256;
        bm0 = fmaxf(bm0, brow[lane]);
        bm1 = fmaxf(bm1, brow[lane + 64]);
        bm2 = fmaxf(bm2, brow[lane + 128]);
        bm3 = fmaxf(bm3, brow[lane + 192]);
        // remove selected element from the owning lane's registers
        if (((bestm >> 2) & 63) == lane) {
            const int jj = ((bestm >> 8) << 2) | (bestm & 3);
            #pragma unroll
            for (int j = 0; j < 8; j++) if (j == jj) v[j] = INFINITY;
        }
    }

    // y = a + max_k b
    float y0 = a0 + bm0, y1 = a1 + bm1, y2 = a2 + bm2, y3 = a3 + bm3;

    // LayerNorm over 256 channels (wave butterfly, all lanes get result)
    float s = y0 + y1 + y2 + y3;
    #pragma unroll
    for (int off = 1; off < 64; off <<= 1) s += __shfl_xor(s, off);
    const float mu = s * (1.0f/256.0f);
    const float d0 = y0 - mu, d1 = y1 - mu, d2 = y2 - mu, d3 = y3 - mu;
    float s2 = d0*d0 + d1*d1 + d2*d2 + d3*d3;
    #pragma unroll
    for (int off = 1; off < 64; off <<= 1) s2 += __shfl_xor(s2, off);
    const float var = s2 * (1.0f/256.0f);
    const float rstd = rsqrtf(var + LN_EPS);

    const float lam = 1.0507009873554805f, alpha = 1.6732632423543772f;
    float* orow = out + (size_t)row * FOUT;
    {
        const float z = d0 * rstd * lsc0 + lbi0;
        orow[lane]       = z > 0.0f ? lam * z : lam * alpha * expm1f(z);
    }
    {
        const float z = d1 * rstd * lsc1 + lbi1;
        orow[lane + 64]  = z > 0.0f ? lam * z : lam * alpha * expm1f(z);
    }
    {
        const float z = d2 * rstd * lsc2 + lbi2;
        orow[lane + 128] = z > 0.0f ? lam * z : lam * alpha * expm1f(z);
    }
    {
        const float z = d3 * rstd * lsc3 + lbi3;
        orow[lane + 192] = z > 0.0f ? lam * z : lam * alpha * expm1f(z);
    }
}

// ---------------------------------------------------------------------------
extern "C" void kernel_launch(void* const* d_in, const int* in_sizes, int n_in,
                              void* d_out, int out_size, void* d_ws, size_t ws_size,
                              hipStream_t stream)
{
    (void)in_sizes; (void)n_in; (void)out_size; (void)ws_size;
    const float* X   = (const float*)d_in[0];
    const float* Wq  = (const float*)d_in[2];
    const float* bq  = (const float*)d_in[3];
    const float* Wk  = (const float*)d_in[4];
    const float* bk  = (const float*)d_in[5];
    const float* Wv  = (const float*)d_in[6];
    const float* bv  = (const float*)d_in[7];
    const float* Wr  = (const float*)d_in[8];
    const float* br  = (const float*)d_in[9];
    const float* Wc  = (const float*)d_in[10];
    const float* bc  = (const float*)d_in[11];
    const float* lns = (const float*)d_in[12];
    const float* lnb = (const float*)d_in[13];
    float* out = (float*)d_out;

    float* ws = (float*)d_ws;
    float* Y  = ws;                              // 8192*512
    float* S  = Y + (size_t)ROWS*512;            // 16*512*512 (scores, then dist)
    float* H  = S + (size_t)NB*NN*NN;            // 8192*128
    float* SQ = H + (size_t)ROWS*HID;            // 8192
    float* AB = SQ + ROWS;                       // 8192*512
    float* D  = S;                               // reuse: S dead after k_hgemm

    k_proj   <<<dim3(8,128),  256, 0, stream>>>(X, Wq,bq, Wk,bk, Wv,bv, Wr,br, Y);
    k_scores <<<dim3(8,8,16), 256, 0, stream>>>(Y, S);
    k_softmax<<<ROWS,         256, 0, stream>>>(S);
    k_hgemm  <<<dim3(2,8,16), 256, 0, stream>>>(S, Y, H);
    k_sq     <<<ROWS/4,       256, 0, stream>>>(H, SQ);
    k_ab     <<<dim3(8,128),  256, 0, stream>>>(H, Wc, bc, AB);
    k_dist   <<<dim3(8,8,16), 256, 0, stream>>>(H, SQ, D);
    k_out    <<<ROWS/4,       256, 0, stream>>>(D, AB, lns, lnb, out);
}

// Round 3
// 232.897 us; speedup vs baseline: 1.9370x; 1.2342x over previous
//
#include <hip/hip_runtime.h>
#include <math.h>

// Problem constants
#define NB   16
#define NN   512
#define FIN  256
#define HID  128
#define FOUT 256
#define TOPK 16
#define ROWS (NB*NN)
#define LN_EPS 1e-5f

// MFMA tiling
#define BM 128
#define BN 128
#define BK 32
#define LDK 40   // padded LDS row (ushort): 80 B -> 16B-aligned frags, 2-way banks only

typedef __attribute__((ext_vector_type(8))) short  bf16x8;
typedef __attribute__((ext_vector_type(4))) float  f32x4;

// ---------------------------------------------------------------------------
// fp32 -> (hi, lo) bf16 split.  x = hi + lo + O(2^-18 |x|)
// ---------------------------------------------------------------------------
__device__ __forceinline__ ushort f2bf_rn(float x) {
    uint u = __float_as_uint(x);
    u += 0x7fff + ((u >> 16) & 1);
    return (ushort)(u >> 16);
}
__device__ __forceinline__ float bf2f(ushort h) {
    return __uint_as_float(((uint)h) << 16);
}
__device__ __forceinline__ void split2(float x, ushort& hi, ushort& lo) {
    hi = f2bf_rn(x);
    lo = f2bf_rn(x - bf2f(hi));   // x - hi is exact (close exponents)
}

// ---------------------------------------------------------------------------
// stage 128 rows x 32 k from row-major source (contiguous k) into split LDS
// ---------------------------------------------------------------------------
__device__ __forceinline__ void stage_rows(ushort (*Dh)[LDK], ushort (*Dl)[LDK],
                                           const float* __restrict__ src,
                                           int rstride, int tid)
{
    const int r = tid >> 1, h = (tid & 1) * 16;
    const float* p = src + (size_t)r * rstride + h;
    #pragma unroll
    for (int i = 0; i < 4; i++) {
        const float4 q = *(const float4*)(p + 4*i);
        ushort hh0, ll0, hh1, ll1, hh2, ll2, hh3, ll3;
        split2(q.x, hh0, ll0); split2(q.y, hh1, ll1);
        split2(q.z, hh2, ll2); split2(q.w, hh3, ll3);
        *(ushort4*)&Dh[r][h + 4*i] = make_ushort4(hh0, hh1, hh2, hh3);
        *(ushort4*)&Dl[r][h + 4*i] = make_ushort4(ll0, ll1, ll2, ll3);
    }
}

// ---------------------------------------------------------------------------
// stage transposed: source is [k][n] row-major (ld = ldn), write [n][k]
// ---------------------------------------------------------------------------
__device__ __forceinline__ void stage_cols(ushort (*Dh)[LDK], ushort (*Dl)[LDK],
                                           const float* __restrict__ src,
                                           int ldn, int tid)
{
    const int n = tid & 127, kh = (tid >> 7) * 16;
    const float* p = src + (size_t)kh * ldn + n;
    #pragma unroll
    for (int ii = 0; ii < 4; ii++) {
        ushort hh[4], ll[4];
        #pragma unroll
        for (int i = 0; i < 4; i++)
            split2(p[(size_t)(4*ii + i) * ldn], hh[i], ll[i]);
        *(ushort4*)&Dh[n][kh + 4*ii] = make_ushort4(hh[0], hh[1], hh[2], hh[3]);
        *(ushort4*)&Dl[n][kh + 4*ii] = make_ushort4(ll[0], ll[1], ll[2], ll[3]);
    }
}

// ---------------------------------------------------------------------------
// one BK=32 step: 4x4 16x16 tiles per wave, 3 MFMAs per tile (split product)
// ---------------------------------------------------------------------------
__device__ __forceinline__ void mma_step(const ushort (*Ah)[LDK], const ushort (*Al)[LDK],
                                         const ushort (*Bh)[LDK], const ushort (*Bl)[LDK],
                                         f32x4 acc[4][4], int wr, int wc, int lane)
{
    const int q8 = (lane >> 4) * 8, m = lane & 15;
    bf16x8 ah[4], al[4], bh[4], bl[4];
    #pragma unroll
    for (int i = 0; i < 4; i++) {
        ah[i] = *(const bf16x8*)&Ah[wr + 16*i + m][q8];
        al[i] = *(const bf16x8*)&Al[wr + 16*i + m][q8];
        bh[i] = *(const bf16x8*)&Bh[wc + 16*i + m][q8];
        bl[i] = *(const bf16x8*)&Bl[wc + 16*i + m][q8];
    }
    #pragma unroll
    for (int i = 0; i < 4; i++)
        #pragma unroll
        for (int j = 0; j < 4; j++) {
            acc[i][j] = __builtin_amdgcn_mfma_f32_16x16x32_bf16(ah[i], bh[j], acc[i][j], 0, 0, 0);
            acc[i][j] = __builtin_amdgcn_mfma_f32_16x16x32_bf16(ah[i], bl[j], acc[i][j], 0, 0, 0);
            acc[i][j] = __builtin_amdgcn_mfma_f32_16x16x32_bf16(al[i], bh[j], acc[i][j], 0, 0, 0);
        }
}

#define MM_PROLOGUE()                                                  \
    __shared__ ushort Ah[BM][LDK], Al[BM][LDK], Bh[BN][LDK], Bl[BN][LDK]; \
    const int tid = threadIdx.x, lane = tid & 63, wv = tid >> 6;       \
    const int wr = (wv >> 1) * 64, wc = (wv & 1) * 64;                 \
    f32x4 acc[4][4];                                                   \
    _Pragma("unroll")                                                  \
    for (int i = 0; i < 4; i++)                                        \
        _Pragma("unroll")                                              \
        for (int j = 0; j < 4; j++)                                    \
            acc[i][j] = (f32x4){0.f, 0.f, 0.f, 0.f};

// ---------------------------------------------------------------------------
// K1: Y[8192,512] = X @ [Wq|Wk|Wv|Wr] + bias   (col-tile = one W)
// ---------------------------------------------------------------------------
__global__ __launch_bounds__(256) void k_proj_m(
    const float* __restrict__ X,
    const float* __restrict__ Wq, const float* __restrict__ bq,
    const float* __restrict__ Wk, const float* __restrict__ bk,
    const float* __restrict__ Wv, const float* __restrict__ bv,
    const float* __restrict__ Wr, const float* __restrict__ br,
    float* __restrict__ Y)
{
    const int ct = blockIdx.x;          // 0..3 -> which W
    const int br0 = blockIdx.y * BM;
    const float* W; const float* bias;
    if      (ct == 0) { W = Wq; bias = bq; }
    else if (ct == 1) { W = Wk; bias = bk; }
    else if (ct == 2) { W = Wv; bias = bv; }
    else              { W = Wr; bias = br; }

    MM_PROLOGUE();

    for (int k0 = 0; k0 < FIN; k0 += BK) {
        stage_rows(Ah, Al, X + (size_t)br0 * FIN + k0, FIN, tid);
        stage_cols(Bh, Bl, W + (size_t)k0 * HID, HID, tid);
        __syncthreads();
        mma_step(Ah, Al, Bh, Bl, acc, wr, wc, lane);
        __syncthreads();
    }

    const int m = lane & 15, q4 = (lane >> 4) * 4;
    #pragma unroll
    for (int i = 0; i < 4; i++)
        #pragma unroll
        for (int reg = 0; reg < 4; reg++) {
            const int grow = br0 + wr + 16*i + q4 + reg;
            #pragma unroll
            for (int j = 0; j < 4; j++) {
                const int c = wc + 16*j + m;
                Y[(size_t)grow * 512 + ct * 128 + c] = acc[i][j][reg] + bias[c];
            }
        }
}

// ---------------------------------------------------------------------------
// K2: S[b,n,m] = (q_n . k_m) / sqrt(HID)
// ---------------------------------------------------------------------------
__global__ __launch_bounds__(256) void k_scores_m(
    const float* __restrict__ Y, float* __restrict__ S)
{
    const int b = blockIdx.z;
    const int m0 = blockIdx.x * BN, n0 = blockIdx.y * BM;
    const float scale = 0.08838834764831845f;
    const float* Yb = Y + (size_t)b * NN * 512;

    MM_PROLOGUE();

    for (int k0 = 0; k0 < HID; k0 += BK) {
        stage_rows(Ah, Al, Yb + (size_t)n0 * 512 + k0,       512, tid);
        stage_rows(Bh, Bl, Yb + (size_t)m0 * 512 + 128 + k0, 512, tid);
        __syncthreads();
        mma_step(Ah, Al, Bh, Bl, acc, wr, wc, lane);
        __syncthreads();
    }

    float* Sb = S + (size_t)b * NN * NN;
    const int m = lane & 15, q4 = (lane >> 4) * 4;
    #pragma unroll
    for (int i = 0; i < 4; i++)
        #pragma unroll
        for (int reg = 0; reg < 4; reg++) {
            const int n = n0 + wr + 16*i + q4 + reg;
            #pragma unroll
            for (int j = 0; j < 4; j++)
                Sb[(size_t)n * NN + m0 + wc + 16*j + m] = acc[i][j][reg] * scale;
        }
}

// ---------------------------------------------------------------------------
// K3: row softmax over 512 (in place)
// ---------------------------------------------------------------------------
__global__ __launch_bounds__(256) void k_softmax(float* __restrict__ S)
{
    float* p = S + (size_t)blockIdx.x * NN;
    const int tid = threadIdx.x;
    const int lane = tid & 63, wave = tid >> 6;
    __shared__ float red[4];

    float v0 = p[tid], v1 = p[tid + 256];
    float mx = fmaxf(v0, v1);
    #pragma unroll
    for (int off = 32; off > 0; off >>= 1) mx = fmaxf(mx, __shfl_down(mx, off));
    if (lane == 0) red[wave] = mx;
    __syncthreads();
    mx = fmaxf(fmaxf(red[0], red[1]), fmaxf(red[2], red[3]));
    __syncthreads();

    float e0 = __expf(v0 - mx), e1 = __expf(v1 - mx);
    float s = e0 + e1;
    #pragma unroll
    for (int off = 32; off > 0; off >>= 1) s += __shfl_down(s, off);
    if (lane == 0) red[wave] = s;
    __syncthreads();
    s = red[0] + red[1] + red[2] + red[3];
    const float inv = 1.0f / s;
    p[tid] = e0 * inv;
    p[tid + 256] = e1 * inv;
}

// ---------------------------------------------------------------------------
// K4: H = P @ V + R   (per batch 512x128, K=512)
// ---------------------------------------------------------------------------
__global__ __launch_bounds__(256) void k_hgemm_m(
    const float* __restrict__ S, const float* __restrict__ Y,
    float* __restrict__ H)
{
    const int n0 = blockIdx.x * BM;
    const int b  = blockIdx.y;
    const float* P = S + (size_t)b * NN * NN;

    MM_PROLOGUE();

    for (int k0 = 0; k0 < NN; k0 += BK) {
        stage_rows(Ah, Al, P + (size_t)n0 * NN + k0, NN, tid);
        stage_cols(Bh, Bl, Y + ((size_t)(b * NN + k0)) * 512 + 256, 512, tid);
        __syncthreads();
        mma_step(Ah, Al, Bh, Bl, acc, wr, wc, lane);
        __syncthreads();
    }

    const int m = lane & 15, q4 = (lane >> 4) * 4;
    #pragma unroll
    for (int i = 0; i < 4; i++)
        #pragma unroll
        for (int reg = 0; reg < 4; reg++) {
            const int gr = b * NN + n0 + wr + 16*i + q4 + reg;
            #pragma unroll
            for (int j = 0; j < 4; j++) {
                const int c = wc + 16*j + m;
                H[(size_t)gr * HID + c] = acc[i][j][reg] + Y[(size_t)gr * 512 + 384 + c];
            }
        }
}

// ---------------------------------------------------------------------------
// K5: per-row squared norm of h
// ---------------------------------------------------------------------------
__global__ __launch_bounds__(256) void k_sq(
    const float* __restrict__ H, float* __restrict__ SQ)
{
    const int row = blockIdx.x * 4 + (threadIdx.x >> 6);
    const int lane = threadIdx.x & 63;
    float a = H[(size_t)row*HID + lane];
    float c = H[(size_t)row*HID + 64 + lane];
    float s = a*a + c*c;
    #pragma unroll
    for (int off = 32; off > 0; off >>= 1) s += __shfl_down(s, off);
    if (lane == 0) SQ[row] = s;
}

// ---------------------------------------------------------------------------
// K6: AB[8192,512]: cols 0:256 = h@(Wc_top-Wc_bot)+bc, 256:512 = h@Wc_bot
// ---------------------------------------------------------------------------
__global__ __launch_bounds__(256) void k_ab_m(
    const float* __restrict__ H, const float* __restrict__ Wc,
    const float* __restrict__ bc, float* __restrict__ AB)
{
    const int ct  = blockIdx.x;            // 0..3
    const int br0 = blockIdx.y * BM;
    const bool bhalf = ct >= 2;
    const int c0 = bhalf ? (ct - 2) * 128 : ct * 128;

    MM_PROLOGUE();

    for (int k0 = 0; k0 < HID; k0 += BK) {
        stage_rows(Ah, Al, H + (size_t)br0 * HID + k0, HID, tid);
        {   // custom transposed staging of (Wtop - Wbot) or Wbot
            const int n = tid & 127, kh = (tid >> 7) * 16;
            #pragma unroll
            for (int ii = 0; ii < 4; ii++) {
                ushort hh[4], ll[4];
                #pragma unroll
                for (int i = 0; i < 4; i++) {
                    const int k = k0 + kh + 4*ii + i;
                    const float wbot = Wc[(size_t)(HID + k) * FOUT + c0 + n];
                    const float val = bhalf ? wbot
                                            : (Wc[(size_t)k * FOUT + c0 + n] - wbot);
                    split2(val, hh[i], ll[i]);
                }
                *(ushort4*)&Bh[n][kh + 4*ii] = make_ushort4(hh[0], hh[1], hh[2], hh[3]);
                *(ushort4*)&Bl[n][kh + 4*ii] = make_ushort4(ll[0], ll[1], ll[2], ll[3]);
            }
        }
        __syncthreads();
        mma_step(Ah, Al, Bh, Bl, acc, wr, wc, lane);
        __syncthreads();
    }

    const int m = lane & 15, q4 = (lane >> 4) * 4;
    #pragma unroll
    for (int i = 0; i < 4; i++)
        #pragma unroll
        for (int reg = 0; reg < 4; reg++) {
            const int grow = br0 + wr + 16*i + q4 + reg;
            #pragma unroll
            for (int j = 0; j < 4; j++) {
                const int c = wc + 16*j + m;
                const float add = bhalf ? 0.0f : bc[c0 + c];
                AB[(size_t)grow * 512 + ct * 128 + c] = acc[i][j][reg] + add;
            }
        }
}

// ---------------------------------------------------------------------------
// K7: D[b,n,m] = SQ[n] + SQ[m] - 2 (h_n . h_m)
// ---------------------------------------------------------------------------
__global__ __launch_bounds__(256) void k_dist_m(
    const float* __restrict__ H, const float* __restrict__ SQ,
    float* __restrict__ D)
{
    const int b = blockIdx.z;
    const int m0 = blockIdx.x * BN, n0 = blockIdx.y * BM;
    const float* Hb = H + (size_t)b * NN * HID;

    MM_PROLOGUE();

    for (int k0 = 0; k0 < HID; k0 += BK) {
        stage_rows(Ah, Al, Hb + (size_t)n0 * HID + k0, HID, tid);
        stage_rows(Bh, Bl, Hb + (size_t)m0 * HID + k0, HID, tid);
        __syncthreads();
        mma_step(Ah, Al, Bh, Bl, acc, wr, wc, lane);
        __syncthreads();
    }

    const int gb = b * NN;
    float* Db = D + (size_t)b * NN * NN;
    const int m = lane & 15, q4 = (lane >> 4) * 4;
    float sqm[4];
    #pragma unroll
    for (int j = 0; j < 4; j++) sqm[j] = SQ[gb + m0 + wc + 16*j + m];
    #pragma unroll
    for (int i = 0; i < 4; i++)
        #pragma unroll
        for (int reg = 0; reg < 4; reg++) {
            const int n = n0 + wr + 16*i + q4 + reg;
            const float sqn = SQ[gb + n];
            #pragma unroll
            for (int j = 0; j < 4; j++)
                Db[(size_t)n * NN + m0 + wc + 16*j + m]
                    = sqn + sqm[j] - 2.0f * acc[i][j][reg];
        }
}

// ---------------------------------------------------------------------------
// K8: per-row top-16 + gather-max + LayerNorm + SELU (wave per row, no LDS)
// ---------------------------------------------------------------------------
__global__ __launch_bounds__(256) void k_out(
    const float* __restrict__ D, const float* __restrict__ AB,
    const float* __restrict__ ln_scale, const float* __restrict__ ln_bias,
    float* __restrict__ out)
{
    const int row  = blockIdx.x * 4 + (threadIdx.x >> 6);
    const int lane = threadIdx.x & 63;
    const int gb0  = row & ~(NN - 1);

    const float* drow = D + (size_t)row * NN;
    const float4 q0 = ((const float4*)drow)[lane];
    const float4 q1 = ((const float4*)drow)[64 + lane];
    float v[8] = {q0.x, q0.y, q0.z, q0.w, q1.x, q1.y, q1.z, q1.w};

    const float lsc0 = ln_scale[lane],       lbi0 = ln_bias[lane];
    const float lsc1 = ln_scale[lane + 64],  lbi1 = ln_bias[lane + 64];
    const float lsc2 = ln_scale[lane + 128], lbi2 = ln_bias[lane + 128];
    const float lsc3 = ln_scale[lane + 192], lbi3 = ln_bias[lane + 192];
    const float* arow = AB + (size_t)row * 512;
    const float a0 = arow[lane], a1 = arow[lane + 64],
                a2 = arow[lane + 128], a3 = arow[lane + 192];

    float bm0 = -INFINITY, bm1 = -INFINITY, bm2 = -INFINITY, bm3 = -INFINITY;

    for (int it = 0; it < TOPK; it++) {
        float bestv = v[0]; int bestm = 4*lane;
        #pragma unroll
        for (int j = 1; j < 8; j++) {
            const int m = (j >> 2)*256 + 4*lane + (j & 3);
            if (v[j] < bestv) { bestv = v[j]; bestm = m; }
        }
        #pragma unroll
        for (int off = 1; off < 64; off <<= 1) {
            const float ov = __shfl_xor(bestv, off);
            const int   om = __shfl_xor(bestm, off);
            if (ov < bestv || (ov == bestv && om < bestm)) { bestv = ov; bestm = om; }
        }
        const float* brow = AB + (size_t)(gb0 + bestm) * 512 + 256;
        bm0 = fmaxf(bm0, brow[lane]);
        bm1 = fmaxf(bm1, brow[lane + 64]);
        bm2 = fmaxf(bm2, brow[lane + 128]);
        bm3 = fmaxf(bm3, brow[lane + 192]);
        if (((bestm >> 2) & 63) == lane) {
            const int jj = ((bestm >> 8) << 2) | (bestm & 3);
            #pragma unroll
            for (int j = 0; j < 8; j++) if (j == jj) v[j] = INFINITY;
        }
    }

    float y0 = a0 + bm0, y1 = a1 + bm1, y2 = a2 + bm2, y3 = a3 + bm3;

    float s = y0 + y1 + y2 + y3;
    #pragma unroll
    for (int off = 1; off < 64; off <<= 1) s += __shfl_xor(s, off);
    const float mu = s * (1.0f/256.0f);
    const float d0 = y0 - mu, d1 = y1 - mu, d2 = y2 - mu, d3 = y3 - mu;
    float s2 = d0*d0 + d1*d1 + d2*d2 + d3*d3;
    #pragma unroll
    for (int off = 1; off < 64; off <<= 1) s2 += __shfl_xor(s2, off);
    const float var = s2 * (1.0f/256.0f);
    const float rstd = rsqrtf(var + LN_EPS);

    const float lam = 1.0507009873554805f, alpha = 1.6732632423543772f;
    float* orow = out + (size_t)row * FOUT;
    { const float z = d0*rstd*lsc0 + lbi0; orow[lane]       = z > 0.f ? lam*z : lam*alpha*expm1f(z); }
    { const float z = d1*rstd*lsc1 + lbi1; orow[lane + 64]  = z > 0.f ? lam*z : lam*alpha*expm1f(z); }
    { const float z = d2*rstd*lsc2 + lbi2; orow[lane + 128] = z > 0.f ? lam*z : lam*alpha*expm1f(z); }
    { const float z = d3*rstd*lsc3 + lbi3; orow[lane + 192] = z > 0.f ? lam*z : lam*alpha*expm1f(z); }
}

// ---------------------------------------------------------------------------
extern "C" void kernel_launch(void* const* d_in, const int* in_sizes, int n_in,
                              void* d_out, int out_size, void* d_ws, size_t ws_size,
                              hipStream_t stream)
{
    (void)in_sizes; (void)n_in; (void)out_size; (void)ws_size;
    const float* X   = (const float*)d_in[0];
    const float* Wq  = (const float*)d_in[2];
    const float* bq  = (const float*)d_in[3];
    const float* Wk  = (const float*)d_in[4];
    const float* bk  = (const float*)d_in[5];
    const float* Wv  = (const float*)d_in[6];
    const float* bv  = (const float*)d_in[7];
    const float* Wr  = (const float*)d_in[8];
    const float* br  = (const float*)d_in[9];
    const float* Wc  = (const float*)d_in[10];
    const float* bc  = (const float*)d_in[11];
    const float* lns = (const float*)d_in[12];
    const float* lnb = (const float*)d_in[13];
    float* out = (float*)d_out;

    float* ws = (float*)d_ws;
    float* Y  = ws;                              // 8192*512
    float* S  = Y + (size_t)ROWS*512;            // 16*512*512 (scores, then dist)
    float* H  = S + (size_t)NB*NN*NN;            // 8192*128
    float* SQ = H + (size_t)ROWS*HID;            // 8192
    float* AB = SQ + ROWS;                       // 8192*512
    float* D  = S;                               // reuse: S dead after k_hgemm

    k_proj_m  <<<dim3(4,64),   256, 0, stream>>>(X, Wq,bq, Wk,bk, Wv,bv, Wr,br, Y);
    k_scores_m<<<dim3(4,4,16), 256, 0, stream>>>(Y, S);
    k_softmax <<<ROWS,         256, 0, stream>>>(S);
    k_hgemm_m <<<dim3(4,16),   256, 0, stream>>>(S, Y, H);
    k_sq      <<<ROWS/4,       256, 0, stream>>>(H, SQ);
    k_ab_m    <<<dim3(4,64),   256, 0, stream>>>(H, Wc, bc, AB);
    k_dist_m  <<<dim3(4,4,16), 256, 0, stream>>>(H, SQ, D);
    k_out     <<<ROWS/4,       256, 0, stream>>>(D, AB, lns, lnb, out);
}

// Round 4
// 198.229 us; speedup vs baseline: 2.2758x; 1.1749x over previous
//
#include <hip/hip_runtime.h>
#include <math.h>

// Problem constants
#define NB   16
#define NN   512
#define FIN  256
#define HID  128
#define FOUT 256
#define TOPK 16
#define ROWS (NB*NN)
#define LN_EPS 1e-5f

// MFMA tiling: 64x64 block tile, BK=32, 20.5 KB LDS -> ~5 blocks/CU
#define BK  32
#define LDK 40   // padded LDS row (ushort): 80 B stride (16B-aligned frags)

typedef __attribute__((ext_vector_type(8))) short  bf16x8;
typedef __attribute__((ext_vector_type(4))) float  f32x4;

// fp32 -> (hi, lo) bf16 split.  x = hi + lo + O(2^-18 |x|)
__device__ __forceinline__ ushort f2bf_rn(float x) {
    uint u = __float_as_uint(x);
    u += 0x7fff + ((u >> 16) & 1);
    return (ushort)(u >> 16);
}
__device__ __forceinline__ float bf2f(ushort h) {
    return __uint_as_float(((uint)h) << 16);
}
__device__ __forceinline__ void split2(float x, ushort& hi, ushort& lo) {
    hi = f2bf_rn(x);
    lo = f2bf_rn(x - bf2f(hi));
}

// stage 64 rows x 32 k from row-major source (contiguous k) into split LDS
__device__ __forceinline__ void stage_rows64(ushort (*Dh)[LDK], ushort (*Dl)[LDK],
                                             const float* __restrict__ src,
                                             int rstride, int tid)
{
    const int r = tid >> 2, seg = (tid & 3) * 8;
    const float* p = src + (size_t)r * rstride + seg;
    #pragma unroll
    for (int i = 0; i < 2; i++) {
        const float4 q = *(const float4*)(p + 4*i);
        ushort h0,l0,h1,l1,h2,l2,h3,l3;
        split2(q.x,h0,l0); split2(q.y,h1,l1);
        split2(q.z,h2,l2); split2(q.w,h3,l3);
        *(ushort4*)&Dh[r][seg + 4*i] = make_ushort4(h0,h1,h2,h3);
        *(ushort4*)&Dl[r][seg + 4*i] = make_ushort4(l0,l1,l2,l3);
    }
}

// stage transposed: source [k][n] row-major (ld = ldn), write [n][k], n=64 wide
__device__ __forceinline__ void stage_cols64(ushort (*Dh)[LDK], ushort (*Dl)[LDK],
                                             const float* __restrict__ src,
                                             int ldn, int tid)
{
    const int n = tid & 63, kh = (tid >> 6) * 8;
    const float* p = src + (size_t)kh * ldn + n;
    ushort hh[8], ll[8];
    #pragma unroll
    for (int i = 0; i < 8; i++) split2(p[(size_t)i * ldn], hh[i], ll[i]);
    *(ushort4*)&Dh[n][kh]     = make_ushort4(hh[0],hh[1],hh[2],hh[3]);
    *(ushort4*)&Dh[n][kh + 4] = make_ushort4(hh[4],hh[5],hh[6],hh[7]);
    *(ushort4*)&Dl[n][kh]     = make_ushort4(ll[0],ll[1],ll[2],ll[3]);
    *(ushort4*)&Dl[n][kh + 4] = make_ushort4(ll[4],ll[5],ll[6],ll[7]);
}

// one BK=32 step: 2x2 16x16 tiles per wave, 3 MFMAs per tile
__device__ __forceinline__ void mma_step64(const ushort (*Ah)[LDK], const ushort (*Al)[LDK],
                                           const ushort (*Bh)[LDK], const ushort (*Bl)[LDK],
                                           f32x4 acc[2][2], int wr, int wc, int lane)
{
    const int q8 = (lane >> 4) * 8, m = lane & 15;
    bf16x8 ah[2], al[2], bh[2], bl[2];
    #pragma unroll
    for (int i = 0; i < 2; i++) {
        ah[i] = *(const bf16x8*)&Ah[wr + 16*i + m][q8];
        al[i] = *(const bf16x8*)&Al[wr + 16*i + m][q8];
        bh[i] = *(const bf16x8*)&Bh[wc + 16*i + m][q8];
        bl[i] = *(const bf16x8*)&Bl[wc + 16*i + m][q8];
    }
    #pragma unroll
    for (int i = 0; i < 2; i++)
        #pragma unroll
        for (int j = 0; j < 2; j++) {
            acc[i][j] = __builtin_amdgcn_mfma_f32_16x16x32_bf16(ah[i], bh[j], acc[i][j], 0, 0, 0);
            acc[i][j] = __builtin_amdgcn_mfma_f32_16x16x32_bf16(ah[i], bl[j], acc[i][j], 0, 0, 0);
            acc[i][j] = __builtin_amdgcn_mfma_f32_16x16x32_bf16(al[i], bh[j], acc[i][j], 0, 0, 0);
        }
}

#define MM64_PROLOGUE()                                                     \
    __shared__ ushort Ah[64][LDK], Al[64][LDK], Bh[64][LDK], Bl[64][LDK];   \
    const int tid = threadIdx.x, lane = tid & 63, wv = tid >> 6;            \
    const int wr = (wv >> 1) * 32, wc = (wv & 1) * 32;                      \
    f32x4 acc[2][2];                                                        \
    _Pragma("unroll")                                                       \
    for (int i = 0; i < 2; i++)                                             \
        _Pragma("unroll")                                                   \
        for (int j = 0; j < 2; j++)                                         \
            acc[i][j] = (f32x4){0.f, 0.f, 0.f, 0.f};

// ---------------------------------------------------------------------------
// K1: Y[8192,512] = X @ [Wq|Wk|Wv|Wr] + bias
// ---------------------------------------------------------------------------
__global__ __launch_bounds__(256) void k_proj_m(
    const float* __restrict__ X,
    const float* __restrict__ Wq, const float* __restrict__ bq,
    const float* __restrict__ Wk, const float* __restrict__ bk,
    const float* __restrict__ Wv, const float* __restrict__ bv,
    const float* __restrict__ Wr, const float* __restrict__ br,
    float* __restrict__ Y)
{
    const int widx = blockIdx.x >> 1;          // which W
    const int ch   = (blockIdx.x & 1) * 64;    // col half within W
    const int br0  = blockIdx.y * 64;
    const float* W; const float* bias;
    if      (widx == 0) { W = Wq; bias = bq; }
    else if (widx == 1) { W = Wk; bias = bk; }
    else if (widx == 2) { W = Wv; bias = bv; }
    else                { W = Wr; bias = br; }

    MM64_PROLOGUE();

    for (int k0 = 0; k0 < FIN; k0 += BK) {
        stage_rows64(Ah, Al, X + (size_t)br0 * FIN + k0, FIN, tid);
        stage_cols64(Bh, Bl, W + (size_t)k0 * HID + ch, HID, tid);
        __syncthreads();
        mma_step64(Ah, Al, Bh, Bl, acc, wr, wc, lane);
        __syncthreads();
    }

    const int m = lane & 15, q4 = (lane >> 4) * 4;
    #pragma unroll
    for (int i = 0; i < 2; i++)
        #pragma unroll
        for (int reg = 0; reg < 4; reg++) {
            const int grow = br0 + wr + 16*i + q4 + reg;
            #pragma unroll
            for (int j = 0; j < 2; j++) {
                const int c = ch + wc + 16*j + m;
                Y[(size_t)grow * 512 + widx * 128 + c] = acc[i][j][reg] + bias[c];
            }
        }
}

// ---------------------------------------------------------------------------
// K2: S[b,n,m] = (q_n . k_m) / sqrt(HID)
// ---------------------------------------------------------------------------
__global__ __launch_bounds__(256) void k_scores_m(
    const float* __restrict__ Y, float* __restrict__ S)
{
    const int b = blockIdx.z;
    const int m0 = blockIdx.x * 64, n0 = blockIdx.y * 64;
    const float scale = 0.08838834764831845f;
    const float* Yb = Y + (size_t)b * NN * 512;

    MM64_PROLOGUE();

    for (int k0 = 0; k0 < HID; k0 += BK) {
        stage_rows64(Ah, Al, Yb + (size_t)n0 * 512 + k0,       512, tid);
        stage_rows64(Bh, Bl, Yb + (size_t)m0 * 512 + 128 + k0, 512, tid);
        __syncthreads();
        mma_step64(Ah, Al, Bh, Bl, acc, wr, wc, lane);
        __syncthreads();
    }

    float* Sb = S + (size_t)b * NN * NN;
    const int m = lane & 15, q4 = (lane >> 4) * 4;
    #pragma unroll
    for (int i = 0; i < 2; i++)
        #pragma unroll
        for (int reg = 0; reg < 4; reg++) {
            const int n = n0 + wr + 16*i + q4 + reg;
            #pragma unroll
            for (int j = 0; j < 2; j++)
                Sb[(size_t)n * NN + m0 + wc + 16*j + m] = acc[i][j][reg] * scale;
        }
}

// ---------------------------------------------------------------------------
// K3: row softmax over 512 (in place)
// ---------------------------------------------------------------------------
__global__ __launch_bounds__(256) void k_softmax(float* __restrict__ S)
{
    float* p = S + (size_t)blockIdx.x * NN;
    const int tid = threadIdx.x;
    const int lane = tid & 63, wave = tid >> 6;
    __shared__ float red[4];

    float v0 = p[tid], v1 = p[tid + 256];
    float mx = fmaxf(v0, v1);
    #pragma unroll
    for (int off = 32; off > 0; off >>= 1) mx = fmaxf(mx, __shfl_down(mx, off));
    if (lane == 0) red[wave] = mx;
    __syncthreads();
    mx = fmaxf(fmaxf(red[0], red[1]), fmaxf(red[2], red[3]));
    __syncthreads();

    float e0 = __expf(v0 - mx), e1 = __expf(v1 - mx);
    float s = e0 + e1;
    #pragma unroll
    for (int off = 32; off > 0; off >>= 1) s += __shfl_down(s, off);
    if (lane == 0) red[wave] = s;
    __syncthreads();
    s = red[0] + red[1] + red[2] + red[3];
    const float inv = 1.0f / s;
    p[tid] = e0 * inv;
    p[tid + 256] = e1 * inv;
}

// ---------------------------------------------------------------------------
// K4: H = P @ V + R   (per batch 512x128, K=512)
// ---------------------------------------------------------------------------
__global__ __launch_bounds__(256) void k_hgemm_m(
    const float* __restrict__ S, const float* __restrict__ Y,
    float* __restrict__ H)
{
    const int c0 = blockIdx.x * 64;   // 0 or 64
    const int n0 = blockIdx.y * 64;
    const int b  = blockIdx.z;
    const float* P = S + (size_t)b * NN * NN;

    MM64_PROLOGUE();

    for (int k0 = 0; k0 < NN; k0 += BK) {
        stage_rows64(Ah, Al, P + (size_t)n0 * NN + k0, NN, tid);
        stage_cols64(Bh, Bl, Y + ((size_t)(b * NN + k0)) * 512 + 256 + c0, 512, tid);
        __syncthreads();
        mma_step64(Ah, Al, Bh, Bl, acc, wr, wc, lane);
        __syncthreads();
    }

    const int m = lane & 15, q4 = (lane >> 4) * 4;
    #pragma unroll
    for (int i = 0; i < 2; i++)
        #pragma unroll
        for (int reg = 0; reg < 4; reg++) {
            const int gr = b * NN + n0 + wr + 16*i + q4 + reg;
            #pragma unroll
            for (int j = 0; j < 2; j++) {
                const int c = c0 + wc + 16*j + m;
                H[(size_t)gr * HID + c] = acc[i][j][reg] + Y[(size_t)gr * 512 + 384 + c];
            }
        }
}

// ---------------------------------------------------------------------------
// K5: per-row squared norm of h
// ---------------------------------------------------------------------------
__global__ __launch_bounds__(256) void k_sq(
    const float* __restrict__ H, float* __restrict__ SQ)
{
    const int row = blockIdx.x * 4 + (threadIdx.x >> 6);
    const int lane = threadIdx.x & 63;
    float a = H[(size_t)row*HID + lane];
    float c = H[(size_t)row*HID + 64 + lane];
    float s = a*a + c*c;
    #pragma unroll
    for (int off = 32; off > 0; off >>= 1) s += __shfl_down(s, off);
    if (lane == 0) SQ[row] = s;
}

// ---------------------------------------------------------------------------
// K6: AB[8192,512]: cols 0:256 = h@(Wc_top-Wc_bot)+bc, 256:512 = h@Wc_bot
// ---------------------------------------------------------------------------
__global__ __launch_bounds__(256) void k_ab_m(
    const float* __restrict__ H, const float* __restrict__ Wc,
    const float* __restrict__ bc, float* __restrict__ AB)
{
    const int ct  = blockIdx.x;            // 0..7 (64-col tiles of AB)
    const int br0 = blockIdx.y * 64;
    const bool bhalf = ct >= 4;
    const int c0 = (ct & 3) * 64;          // col offset within the 256-wide half

    MM64_PROLOGUE();

    for (int k0 = 0; k0 < HID; k0 += BK) {
        stage_rows64(Ah, Al, H + (size_t)br0 * HID + k0, HID, tid);
        {   // transposed staging of (Wtop - Wbot) or Wbot
            const int n = tid & 63, kh = (tid >> 6) * 8;
            ushort hh[8], ll[8];
            #pragma unroll
            for (int i = 0; i < 8; i++) {
                const int k = k0 + kh + i;
                const float wbot = Wc[(size_t)(HID + k) * FOUT + c0 + n];
                const float val = bhalf ? wbot
                                        : (Wc[(size_t)k * FOUT + c0 + n] - wbot);
                split2(val, hh[i], ll[i]);
            }
            *(ushort4*)&Bh[n][kh]     = make_ushort4(hh[0],hh[1],hh[2],hh[3]);
            *(ushort4*)&Bh[n][kh + 4] = make_ushort4(hh[4],hh[5],hh[6],hh[7]);
            *(ushort4*)&Bl[n][kh]     = make_ushort4(ll[0],ll[1],ll[2],ll[3]);
            *(ushort4*)&Bl[n][kh + 4] = make_ushort4(ll[4],ll[5],ll[6],ll[7]);
        }
        __syncthreads();
        mma_step64(Ah, Al, Bh, Bl, acc, wr, wc, lane);
        __syncthreads();
    }

    const int m = lane & 15, q4 = (lane >> 4) * 4;
    #pragma unroll
    for (int i = 0; i < 2; i++)
        #pragma unroll
        for (int reg = 0; reg < 4; reg++) {
            const int grow = br0 + wr + 16*i + q4 + reg;
            #pragma unroll
            for (int j = 0; j < 2; j++) {
                const int c = wc + 16*j + m;
                const float add = bhalf ? 0.0f : bc[c0 + c];
                AB[(size_t)grow * 512 + ct * 64 + c] = acc[i][j][reg] + add;
            }
        }
}

// ---------------------------------------------------------------------------
// K7: D[b,n,m] = SQ[n] + SQ[m] - 2 (h_n . h_m)
// ---------------------------------------------------------------------------
__global__ __launch_bounds__(256) void k_dist_m(
    const float* __restrict__ H, const float* __restrict__ SQ,
    float* __restrict__ D)
{
    const int b = blockIdx.z;
    const int m0 = blockIdx.x * 64, n0 = blockIdx.y * 64;
    const float* Hb = H + (size_t)b * NN * HID;

    MM64_PROLOGUE();

    for (int k0 = 0; k0 < HID; k0 += BK) {
        stage_rows64(Ah, Al, Hb + (size_t)n0 * HID + k0, HID, tid);
        stage_rows64(Bh, Bl, Hb + (size_t)m0 * HID + k0, HID, tid);
        __syncthreads();
        mma_step64(Ah, Al, Bh, Bl, acc, wr, wc, lane);
        __syncthreads();
    }

    const int gb = b * NN;
    float* Db = D + (size_t)b * NN * NN;
    const int m = lane & 15, q4 = (lane >> 4) * 4;
    float sqm[2];
    #pragma unroll
    for (int j = 0; j < 2; j++) sqm[j] = SQ[gb + m0 + wc + 16*j + m];
    #pragma unroll
    for (int i = 0; i < 2; i++)
        #pragma unroll
        for (int reg = 0; reg < 4; reg++) {
            const int n = n0 + wr + 16*i + q4 + reg;
            const float sqn = SQ[gb + n];
            #pragma unroll
            for (int j = 0; j < 2; j++)
                Db[(size_t)n * NN + m0 + wc + 16*j + m]
                    = sqn + sqm[j] - 2.0f * acc[i][j][reg];
        }
}

// ---------------------------------------------------------------------------
// K8: per-row top-16 + gather-max + LayerNorm + SELU (wave per row, no LDS)
// ---------------------------------------------------------------------------
__global__ __launch_bounds__(256) void k_out(
    const float* __restrict__ D, const float* __restrict__ AB,
    const float* __restrict__ ln_scale, const float* __restrict__ ln_bias,
    float* __restrict__ out)
{
    const int row  = blockIdx.x * 4 + (threadIdx.x >> 6);
    const int lane = threadIdx.x & 63;
    const int gb0  = row & ~(NN - 1);

    const float* drow = D + (size_t)row * NN;
    const float4 q0 = ((const float4*)drow)[lane];
    const float4 q1 = ((const float4*)drow)[64 + lane];
    float v[8] = {q0.x, q0.y, q0.z, q0.w, q1.x, q1.y, q1.z, q1.w};

    const float lsc0 = ln_scale[lane],       lbi0 = ln_bias[lane];
    const float lsc1 = ln_scale[lane + 64],  lbi1 = ln_bias[lane + 64];
    const float lsc2 = ln_scale[lane + 128], lbi2 = ln_bias[lane + 128];
    const float lsc3 = ln_scale[lane + 192], lbi3 = ln_bias[lane + 192];
    const float* arow = AB + (size_t)row * 512;
    const float a0 = arow[lane], a1 = arow[lane + 64],
                a2 = arow[lane + 128], a3 = arow[lane + 192];

    float bm0 = -INFINITY, bm1 = -INFINITY, bm2 = -INFINITY, bm3 = -INFINITY;

    for (int it = 0; it < TOPK; it++) {
        float bestv = v[0]; int bestm = 4*lane;
        #pragma unroll
        for (int j = 1; j < 8; j++) {
            const int m = (j >> 2)*256 + 4*lane + (j & 3);
            if (v[j] < bestv) { bestv = v[j]; bestm = m; }
        }
        #pragma unroll
        for (int off = 1; off < 64; off <<= 1) {
            const float ov = __shfl_xor(bestv, off);
            const int   om = __shfl_xor(bestm, off);
            if (ov < bestv || (ov == bestv && om < bestm)) { bestv = ov; bestm = om; }
        }
        const float* brow = AB + (size_t)(gb0 + bestm) * 512 + 256;
        bm0 = fmaxf(bm0, brow[lane]);
        bm1 = fmaxf(bm1, brow[lane + 64]);
        bm2 = fmaxf(bm2, brow[lane + 128]);
        bm3 = fmaxf(bm3, brow[lane + 192]);
        if (((bestm >> 2) & 63) == lane) {
            const int jj = ((bestm >> 8) << 2) | (bestm & 3);
            #pragma unroll
            for (int j = 0; j < 8; j++) if (j == jj) v[j] = INFINITY;
        }
    }

    float y0 = a0 + bm0, y1 = a1 + bm1, y2 = a2 + bm2, y3 = a3 + bm3;

    float s = y0 + y1 + y2 + y3;
    #pragma unroll
    for (int off = 1; off < 64; off <<= 1) s += __shfl_xor(s, off);
    const float mu = s * (1.0f/256.0f);
    const float d0 = y0 - mu, d1 = y1 - mu, d2 = y2 - mu, d3 = y3 - mu;
    float s2 = d0*d0 + d1*d1 + d2*d2 + d3*d3;
    #pragma unroll
    for (int off = 1; off < 64; off <<= 1) s2 += __shfl_xor(s2, off);
    const float var = s2 * (1.0f/256.0f);
    const float rstd = rsqrtf(var + LN_EPS);

    const float lam = 1.0507009873554805f, alpha = 1.6732632423543772f;
    float* orow = out + (size_t)row * FOUT;
    { const float z = d0*rstd*lsc0 + lbi0; orow[lane]       = z > 0.f ? lam*z : lam*alpha*expm1f(z); }
    { const float z = d1*rstd*lsc1 + lbi1; orow[lane + 64]  = z > 0.f ? lam*z : lam*alpha*expm1f(z); }
    { const float z = d2*rstd*lsc2 + lbi2; orow[lane + 128] = z > 0.f ? lam*z : lam*alpha*expm1f(z); }
    { const float z = d3*rstd*lsc3 + lbi3; orow[lane + 192] = z > 0.f ? lam*z : lam*alpha*expm1f(z); }
}

// ---------------------------------------------------------------------------
extern "C" void kernel_launch(void* const* d_in, const int* in_sizes, int n_in,
                              void* d_out, int out_size, void* d_ws, size_t ws_size,
                              hipStream_t stream)
{
    (void)in_sizes; (void)n_in; (void)out_size; (void)ws_size;
    const float* X   = (const float*)d_in[0];
    const float* Wq  = (const float*)d_in[2];
    const float* bq  = (const float*)d_in[3];
    const float* Wk  = (const float*)d_in[4];
    const float* bk  = (const float*)d_in[5];
    const float* Wv  = (const float*)d_in[6];
    const float* bv  = (const float*)d_in[7];
    const float* Wr  = (const float*)d_in[8];
    const float* br  = (const float*)d_in[9];
    const float* Wc  = (const float*)d_in[10];
    const float* bc  = (const float*)d_in[11];
    const float* lns = (const float*)d_in[12];
    const float* lnb = (const float*)d_in[13];
    float* out = (float*)d_out;

    float* ws = (float*)d_ws;
    float* Y  = ws;                              // 8192*512
    float* S  = Y + (size_t)ROWS*512;            // 16*512*512 (scores, then dist)
    float* H  = S + (size_t)NB*NN*NN;            // 8192*128
    float* SQ = H + (size_t)ROWS*HID;            // 8192
    float* AB = SQ + ROWS;                       // 8192*512
    float* D  = S;                               // reuse: S dead after k_hgemm

    k_proj_m  <<<dim3(8,128),  256, 0, stream>>>(X, Wq,bq, Wk,bk, Wv,bv, Wr,br, Y);
    k_scores_m<<<dim3(8,8,16), 256, 0, stream>>>(Y, S);
    k_softmax <<<ROWS,         256, 0, stream>>>(S);
    k_hgemm_m <<<dim3(2,8,16), 256, 0, stream>>>(S, Y, H);
    k_sq      <<<ROWS/4,       256, 0, stream>>>(H, SQ);
    k_ab_m    <<<dim3(8,128),  256, 0, stream>>>(H, Wc, bc, AB);
    k_dist_m  <<<dim3(8,8,16), 256, 0, stream>>>(H, SQ, D);
    k_out     <<<ROWS/4,       256, 0, stream>>>(D, AB, lns, lnb, out);
}

// Round 5
// 196.540 us; speedup vs baseline: 2.2954x; 1.0086x over previous
//
#include <hip/hip_runtime.h>
#include <math.h>

// Problem constants
#define NB   16
#define NN   512
#define FIN  256
#define HID  128
#define FOUT 256
#define TOPK 16
#define ROWS (NB*NN)
#define LN_EPS 1e-5f

// MFMA tiling: 64x64 block tile, BK=32
#define BK  32
#define LDK 40   // padded LDS row (ushort): 80 B stride, 16B-aligned frags

typedef __attribute__((ext_vector_type(8)))  short  bf16x8;
typedef __attribute__((ext_vector_type(4)))  float  f32x4;
typedef __attribute__((ext_vector_type(8)))  unsigned short u16x8;

// fp32 -> (hi, lo) bf16 split.  x = hi + lo + O(2^-18 |x|)
__device__ __forceinline__ ushort f2bf_rn(float x) {
    uint u = __float_as_uint(x);
    u += 0x7fff + ((u >> 16) & 1);
    return (ushort)(u >> 16);
}
__device__ __forceinline__ float bf2f(ushort h) {
    return __uint_as_float(((uint)h) << 16);
}
__device__ __forceinline__ void split2(float x, ushort& hi, ushort& lo) {
    hi = f2bf_rn(x);
    lo = f2bf_rn(x - bf2f(hi));
}

// stage 64 rows x 32 k of a pre-split ushort plane into LDS (pure copy)
__device__ __forceinline__ void stage_u(ushort (*Ds)[LDK], const ushort* __restrict__ src,
                                        int rstride, int tid)
{
    const int r = tid >> 2, seg = (tid & 3) * 8;
    *(u16x8*)&Ds[r][seg] = *(const u16x8*)(src + (size_t)r * rstride + seg);
}

// one BK=32 step: 2x2 16x16 tiles per wave, 3 MFMAs per tile (split product)
__device__ __forceinline__ void mma_step64(const ushort (*Ah)[LDK], const ushort (*Al)[LDK],
                                           const ushort (*Bh)[LDK], const ushort (*Bl)[LDK],
                                           f32x4 acc[2][2], int wr, int wc, int lane)
{
    const int q8 = (lane >> 4) * 8, m = lane & 15;
    bf16x8 ah[2], al[2], bh[2], bl[2];
    #pragma unroll
    for (int i = 0; i < 2; i++) {
        ah[i] = *(const bf16x8*)&Ah[wr + 16*i + m][q8];
        al[i] = *(const bf16x8*)&Al[wr + 16*i + m][q8];
        bh[i] = *(const bf16x8*)&Bh[wc + 16*i + m][q8];
        bl[i] = *(const bf16x8*)&Bl[wc + 16*i + m][q8];
    }
    #pragma unroll
    for (int i = 0; i < 2; i++)
        #pragma unroll
        for (int j = 0; j < 2; j++) {
            acc[i][j] = __builtin_amdgcn_mfma_f32_16x16x32_bf16(ah[i], bh[j], acc[i][j], 0, 0, 0);
            acc[i][j] = __builtin_amdgcn_mfma_f32_16x16x32_bf16(ah[i], bl[j], acc[i][j], 0, 0, 0);
            acc[i][j] = __builtin_amdgcn_mfma_f32_16x16x32_bf16(al[i], bh[j], acc[i][j], 0, 0, 0);
        }
}

#define MM64_PROLOGUE()                                                     \
    __shared__ ushort smem[4*64*LDK];                                       \
    ushort (*Ah)[LDK] = (ushort (*)[LDK])(smem);                            \
    ushort (*Al)[LDK] = (ushort (*)[LDK])(smem + 64*LDK);                   \
    ushort (*Bh)[LDK] = (ushort (*)[LDK])(smem + 2*64*LDK);                 \
    ushort (*Bl)[LDK] = (ushort (*)[LDK])(smem + 3*64*LDK);                 \
    float* fbuf = (float*)smem;  /* epilogue reuse: 64x65 fp32 = 16.6 KB */ \
    const int tid = threadIdx.x, lane = tid & 63, wv = tid >> 6;            \
    const int wr = (wv >> 1) * 32, wc = (wv & 1) * 32;                      \
    f32x4 acc[2][2];                                                        \
    _Pragma("unroll")                                                       \
    for (int i = 0; i < 2; i++)                                             \
        _Pragma("unroll")                                                   \
        for (int j = 0; j < 2; j++)                                         \
            acc[i][j] = (f32x4){0.f, 0.f, 0.f, 0.f};

// ---------------------------------------------------------------------------
// P0: prep weights: Wt[512][256] hi/lo (transposed concat of Wq..Wr),
//     Wct[512][128] hi/lo (n<256: Wc_top-Wc_bot; else Wc_bot), bcat, bcab,
//     zero SQ.
// ---------------------------------------------------------------------------
__global__ __launch_bounds__(256) void k_prep_w(
    const float* __restrict__ Wq, const float* __restrict__ Wk,
    const float* __restrict__ Wv, const float* __restrict__ Wr,
    const float* __restrict__ Wc,
    const float* __restrict__ bq, const float* __restrict__ bk,
    const float* __restrict__ bv, const float* __restrict__ br,
    const float* __restrict__ bc,
    ushort* __restrict__ Wth, ushort* __restrict__ Wtl,
    ushort* __restrict__ Wcth, ushort* __restrict__ Wctl,
    float* __restrict__ bcat, float* __restrict__ bcab,
    float* __restrict__ SQ)
{
    const int blk = blockIdx.x, tid = threadIdx.x;
    __shared__ float fb[64][65];

    if (blk < 8) {                       // Wt tiles: n0 = blk*64
        const int n0 = blk * 64;
        const int widx = n0 >> 7;
        const float* W = widx==0 ? Wq : widx==1 ? Wk : widx==2 ? Wv : Wr;
        const int cbase = n0 & 127;
        for (int kt = 0; kt < 4; kt++) {
            const int k0 = kt * 64;
            __syncthreads();
            {
                const int kk = tid >> 2, cs = (tid & 3) * 16;
                #pragma unroll
                for (int t = 0; t < 16; t += 4) {
                    const float4 q = *(const float4*)&W[(size_t)(k0+kk)*HID + cbase + cs + t];
                    fb[kk][cs+t]=q.x; fb[kk][cs+t+1]=q.y; fb[kk][cs+t+2]=q.z; fb[kk][cs+t+3]=q.w;
                }
            }
            __syncthreads();
            {
                const int c = tid >> 2, ks = (tid & 3) * 16;
                u16x8 vh0, vh1, vl0, vl1;
                #pragma unroll
                for (int t = 0; t < 8; t++) {
                    ushort hh, ll;
                    split2(fb[ks+t][c], hh, ll); vh0[t]=hh; vl0[t]=ll;
                    split2(fb[ks+8+t][c], hh, ll); vh1[t]=hh; vl1[t]=ll;
                }
                *(u16x8*)&Wth[(size_t)(n0+c)*256 + k0 + ks]     = vh0;
                *(u16x8*)&Wth[(size_t)(n0+c)*256 + k0 + ks + 8] = vh1;
                *(u16x8*)&Wtl[(size_t)(n0+c)*256 + k0 + ks]     = vl0;
                *(u16x8*)&Wtl[(size_t)(n0+c)*256 + k0 + ks + 8] = vl1;
            }
        }
    } else if (blk < 16) {               // Wct tiles: n0 = (blk-8)*64
        const int n0 = (blk - 8) * 64;
        const bool ahalf = n0 < 256;
        const int cbase = n0 & 255;
        for (int kt = 0; kt < 2; kt++) {
            const int k0 = kt * 64;
            __syncthreads();
            {
                const int kk = tid >> 2, cs = (tid & 3) * 16;
                #pragma unroll
                for (int t = 0; t < 16; t++) {
                    const float bot = Wc[(size_t)(HID + k0 + kk)*FOUT + cbase + cs + t];
                    float val = bot;
                    if (ahalf) val = Wc[(size_t)(k0 + kk)*FOUT + cbase + cs + t] - bot;
                    fb[kk][cs+t] = val;
                }
            }
            __syncthreads();
            {
                const int c = tid >> 2, ks = (tid & 3) * 16;
                u16x8 vh0, vh1, vl0, vl1;
                #pragma unroll
                for (int t = 0; t < 8; t++) {
                    ushort hh, ll;
                    split2(fb[ks+t][c], hh, ll); vh0[t]=hh; vl0[t]=ll;
                    split2(fb[ks+8+t][c], hh, ll); vh1[t]=hh; vl1[t]=ll;
                }
                *(u16x8*)&Wcth[(size_t)(n0+c)*128 + k0 + ks]     = vh0;
                *(u16x8*)&Wcth[(size_t)(n0+c)*128 + k0 + ks + 8] = vh1;
                *(u16x8*)&Wctl[(size_t)(n0+c)*128 + k0 + ks]     = vl0;
                *(u16x8*)&Wctl[(size_t)(n0+c)*128 + k0 + ks + 8] = vl1;
            }
        }
    } else {                             // scalars
        for (int i = tid; i < 512; i += 256) {
            const int w = i >> 7, c = i & 127;
            bcat[i] = w==0 ? bq[c] : w==1 ? bk[c] : w==2 ? bv[c] : br[c];
            bcab[i] = i < 256 ? bc[i] : 0.f;
        }
        for (int i = tid; i < ROWS; i += 256) SQ[i] = 0.f;
    }
}

// ---------------------------------------------------------------------------
// P1: split X into hi/lo planes
// ---------------------------------------------------------------------------
__global__ __launch_bounds__(256) void k_prep_x(
    const float* __restrict__ X, ushort* __restrict__ Xh, ushort* __restrict__ Xl)
{
    const size_t base = ((size_t)blockIdx.x * 256 + threadIdx.x) * 8;
    const float4 a = *(const float4*)(X + base);
    const float4 b = *(const float4*)(X + base + 4);
    u16x8 vh, vl; ushort hh, ll;
    split2(a.x,hh,ll); vh[0]=hh; vl[0]=ll;
    split2(a.y,hh,ll); vh[1]=hh; vl[1]=ll;
    split2(a.z,hh,ll); vh[2]=hh; vl[2]=ll;
    split2(a.w,hh,ll); vh[3]=hh; vl[3]=ll;
    split2(b.x,hh,ll); vh[4]=hh; vl[4]=ll;
    split2(b.y,hh,ll); vh[5]=hh; vl[5]=ll;
    split2(b.z,hh,ll); vh[6]=hh; vl[6]=ll;
    split2(b.w,hh,ll); vh[7]=hh; vl[7]=ll;
    *(u16x8*)(Xh + base) = vh;
    *(u16x8*)(Xl + base) = vl;
}

// ---------------------------------------------------------------------------
// K1: projection GEMM. ct 0..3 -> q|k planes [8192][256]; ct 4,5 -> V
//     transposed planes [b][128][512]; ct 6,7 -> R fp32 [8192][128].
// ---------------------------------------------------------------------------
__global__ __launch_bounds__(256) void k_proj_m(
    const ushort* __restrict__ Xh, const ushort* __restrict__ Xl,
    const ushort* __restrict__ Wth, const ushort* __restrict__ Wtl,
    const float* __restrict__ bcat,
    ushort* __restrict__ Yh, ushort* __restrict__ Yl,
    ushort* __restrict__ Vth, ushort* __restrict__ Vtl,
    float* __restrict__ Rbuf)
{
    const int ct  = blockIdx.x;          // 64-col tile of Wcat (0..7)
    const int br0 = blockIdx.y * 64;     // global row

    MM64_PROLOGUE();

    for (int k0 = 0; k0 < FIN; k0 += BK) {
        stage_u(Ah, Xh + (size_t)br0 * 256 + k0, 256, tid);
        stage_u(Al, Xl + (size_t)br0 * 256 + k0, 256, tid);
        stage_u(Bh, Wth + (size_t)(ct*64) * 256 + k0, 256, tid);
        stage_u(Bl, Wtl + (size_t)(ct*64) * 256 + k0, 256, tid);
        __syncthreads();
        mma_step64(Ah, Al, Bh, Bl, acc, wr, wc, lane);
        __syncthreads();
    }

    // write acc + bias into fbuf[64][65]
    {
        const int m = lane & 15, q4 = (lane >> 4) * 4;
        #pragma unroll
        for (int i = 0; i < 2; i++)
            #pragma unroll
            for (int reg = 0; reg < 4; reg++) {
                const int r = wr + 16*i + q4 + reg;
                #pragma unroll
                for (int j = 0; j < 2; j++) {
                    const int c = wc + 16*j + m;
                    fbuf[r*65 + c] = acc[i][j][reg] + bcat[ct*64 + c];
                }
            }
    }
    __syncthreads();

    if (ct < 4) {            // q|k planes, row-major
        const int r = tid >> 2, cs = (tid & 3) * 16;
        u16x8 vh0, vh1, vl0, vl1;
        #pragma unroll
        for (int t = 0; t < 8; t++) {
            ushort hh, ll;
            split2(fbuf[r*65 + cs + t], hh, ll);     vh0[t]=hh; vl0[t]=ll;
            split2(fbuf[r*65 + cs + 8 + t], hh, ll); vh1[t]=hh; vl1[t]=ll;
        }
        const size_t o = (size_t)(br0 + r) * 256 + ct*64 + cs;
        *(u16x8*)&Yh[o]   = vh0; *(u16x8*)&Yh[o+8] = vh1;
        *(u16x8*)&Yl[o]   = vl0; *(u16x8*)&Yl[o+8] = vl1;
    } else if (ct < 6) {     // V transposed planes
        const int cl = tid >> 2, rs = (tid & 3) * 16;
        const int b = br0 >> 9, nb = br0 & 511;
        const int cglob = (ct - 4) * 64 + cl;
        u16x8 vh0, vh1, vl0, vl1;
        #pragma unroll
        for (int t = 0; t < 8; t++) {
            ushort hh, ll;
            split2(fbuf[(rs+t)*65 + cl], hh, ll);   vh0[t]=hh; vl0[t]=ll;
            split2(fbuf[(rs+8+t)*65 + cl], hh, ll); vh1[t]=hh; vl1[t]=ll;
        }
        const size_t o = ((size_t)b*128 + cglob) * 512 + nb + rs;
        *(u16x8*)&Vth[o]   = vh0; *(u16x8*)&Vth[o+8] = vh1;
        *(u16x8*)&Vtl[o]   = vl0; *(u16x8*)&Vtl[o+8] = vl1;
    } else {                 // R fp32 [8192][128]
        const int r = tid >> 2, cs = (tid & 3) * 16;
        float* dst = Rbuf + (size_t)(br0 + r) * 128 + (ct - 6)*64 + cs;
        #pragma unroll
        for (int t = 0; t < 16; t += 4) {
            float4 q;
            q.x = fbuf[r*65+cs+t];   q.y = fbuf[r*65+cs+t+1];
            q.z = fbuf[r*65+cs+t+2]; q.w = fbuf[r*65+cs+t+3];
            *(float4*)(dst + t) = q;
        }
    }
}

// ---------------------------------------------------------------------------
// K2: S[b,n,m] = (q_n . k_m) / sqrt(HID)   (fp32 out)
// ---------------------------------------------------------------------------
__global__ __launch_bounds__(256) void k_scores_m(
    const ushort* __restrict__ Yh, const ushort* __restrict__ Yl,
    float* __restrict__ S)
{
    const int b = blockIdx.z;
    const int m0 = blockIdx.x * 64, n0 = blockIdx.y * 64;
    const float scale = 0.08838834764831845f;

    MM64_PROLOGUE();

    for (int k0 = 0; k0 < HID; k0 += BK) {
        stage_u(Ah, Yh + (size_t)(b*NN + n0) * 256 + k0,       256, tid);
        stage_u(Al, Yl + (size_t)(b*NN + n0) * 256 + k0,       256, tid);
        stage_u(Bh, Yh + (size_t)(b*NN + m0) * 256 + 128 + k0, 256, tid);
        stage_u(Bl, Yl + (size_t)(b*NN + m0) * 256 + 128 + k0, 256, tid);
        __syncthreads();
        mma_step64(Ah, Al, Bh, Bl, acc, wr, wc, lane);
        __syncthreads();
    }

    float* Sb = S + (size_t)b * NN * NN;
    const int m = lane & 15, q4 = (lane >> 4) * 4;
    #pragma unroll
    for (int i = 0; i < 2; i++)
        #pragma unroll
        for (int reg = 0; reg < 4; reg++) {
            const int n = n0 + wr + 16*i + q4 + reg;
            #pragma unroll
            for (int j = 0; j < 2; j++)
                Sb[(size_t)n * NN + m0 + wc + 16*j + m] = acc[i][j][reg] * scale;
        }
}

// ---------------------------------------------------------------------------
// K3: row softmax over 512; writes split bf16 P planes
// ---------------------------------------------------------------------------
__global__ __launch_bounds__(256) void k_softmax2(
    const float* __restrict__ S, ushort* __restrict__ Ph, ushort* __restrict__ Pl)
{
    const size_t row = blockIdx.x;
    const float* p = S + row * NN;
    const int tid = threadIdx.x, lane = tid & 63, wave = tid >> 6;
    __shared__ float red[4];

    const float2 vv = ((const float2*)p)[tid];
    float mx = fmaxf(vv.x, vv.y);
    #pragma unroll
    for (int off = 32; off > 0; off >>= 1) mx = fmaxf(mx, __shfl_down(mx, off));
    if (lane == 0) red[wave] = mx;
    __syncthreads();
    mx = fmaxf(fmaxf(red[0], red[1]), fmaxf(red[2], red[3]));
    __syncthreads();

    const float e0 = __expf(vv.x - mx), e1 = __expf(vv.y - mx);
    float s = e0 + e1;
    #pragma unroll
    for (int off = 32; off > 0; off >>= 1) s += __shfl_down(s, off);
    if (lane == 0) red[wave] = s;
    __syncthreads();
    s = red[0] + red[1] + red[2] + red[3];
    const float inv = 1.0f / s;

    ushort h0,l0,h1,l1;
    split2(e0 * inv, h0, l0);
    split2(e1 * inv, h1, l1);
    ((ushort2*)Ph)[row * 256 + tid] = make_ushort2(h0, h1);
    ((ushort2*)Pl)[row * 256 + tid] = make_ushort2(l0, l1);
}

// ---------------------------------------------------------------------------
// K4: H = P @ V + R; writes split H planes + SQ (atomic per-row |h|^2)
// ---------------------------------------------------------------------------
__global__ __launch_bounds__(256) void k_hgemm_m(
    const ushort* __restrict__ Ph, const ushort* __restrict__ Pl,
    const ushort* __restrict__ Vth, const ushort* __restrict__ Vtl,
    const float* __restrict__ Rbuf,
    ushort* __restrict__ Hh, ushort* __restrict__ Hl,
    float* __restrict__ SQ)
{
    const int c0 = blockIdx.x * 64;   // 0 or 64
    const int n0 = blockIdx.y * 64;
    const int b  = blockIdx.z;

    MM64_PROLOGUE();

    for (int k0 = 0; k0 < NN; k0 += BK) {
        stage_u(Ah, Ph + (size_t)(b*NN + n0) * 512 + k0, 512, tid);
        stage_u(Al, Pl + (size_t)(b*NN + n0) * 512 + k0, 512, tid);
        stage_u(Bh, Vth + ((size_t)b*128 + c0) * 512 + k0, 512, tid);
        stage_u(Bl, Vtl + ((size_t)b*128 + c0) * 512 + k0, 512, tid);
        __syncthreads();
        mma_step64(Ah, Al, Bh, Bl, acc, wr, wc, lane);
        __syncthreads();
    }

    {   // raw acc -> fbuf
        const int m = lane & 15, q4 = (lane >> 4) * 4;
        #pragma unroll
        for (int i = 0; i < 2; i++)
            #pragma unroll
            for (int reg = 0; reg < 4; reg++) {
                const int r = wr + 16*i + q4 + reg;
                #pragma unroll
                for (int j = 0; j < 2; j++)
                    fbuf[r*65 + wc + 16*j + m] = acc[i][j][reg];
            }
    }
    __syncthreads();

    {   // + R, write split planes, SQ partial
        const int r = tid >> 2, cs = (tid & 3) * 16;
        const int gr = b*NN + n0 + r;
        const float* rp = Rbuf + (size_t)gr * 128 + c0 + cs;
        float h[16]; float sqp = 0.f;
        #pragma unroll
        for (int t = 0; t < 16; t += 4) {
            const float4 q = *(const float4*)(rp + t);
            h[t]   = fbuf[r*65+cs+t]   + q.x;
            h[t+1] = fbuf[r*65+cs+t+1] + q.y;
            h[t+2] = fbuf[r*65+cs+t+2] + q.z;
            h[t+3] = fbuf[r*65+cs+t+3] + q.w;
        }
        u16x8 vh0, vh1, vl0, vl1;
        #pragma unroll
        for (int t = 0; t < 8; t++) {
            ushort hh, ll;
            split2(h[t], hh, ll);   vh0[t]=hh; vl0[t]=ll;
            split2(h[8+t], hh, ll); vh1[t]=hh; vl1[t]=ll;
            sqp += h[t]*h[t] + h[8+t]*h[8+t];
        }
        const size_t o = (size_t)gr * 128 + c0 + cs;
        *(u16x8*)&Hh[o]   = vh0; *(u16x8*)&Hh[o+8] = vh1;
        *(u16x8*)&Hl[o]   = vl0; *(u16x8*)&Hl[o+8] = vl1;
        sqp += __shfl_xor(sqp, 1);
        sqp += __shfl_xor(sqp, 2);
        if ((tid & 3) == 0) atomicAdd(&SQ[gr], sqp);
    }
}

// ---------------------------------------------------------------------------
// K5: AB[8192,512] fp32: a-half uses Wct (top-bot) + bc, b-half uses Wc_bot
// ---------------------------------------------------------------------------
__global__ __launch_bounds__(256) void k_ab_m(
    const ushort* __restrict__ Hh, const ushort* __restrict__ Hl,
    const ushort* __restrict__ Wcth, const ushort* __restrict__ Wctl,
    const float* __restrict__ bcab, float* __restrict__ AB)
{
    const int ct  = blockIdx.x;            // 0..7
    const int br0 = blockIdx.y * 64;

    MM64_PROLOGUE();

    for (int k0 = 0; k0 < HID; k0 += BK) {
        stage_u(Ah, Hh + (size_t)br0 * 128 + k0, 128, tid);
        stage_u(Al, Hl + (size_t)br0 * 128 + k0, 128, tid);
        stage_u(Bh, Wcth + (size_t)(ct*64) * 128 + k0, 128, tid);
        stage_u(Bl, Wctl + (size_t)(ct*64) * 128 + k0, 128, tid);
        __syncthreads();
        mma_step64(Ah, Al, Bh, Bl, acc, wr, wc, lane);
        __syncthreads();
    }

    const int m = lane & 15, q4 = (lane >> 4) * 4;
    #pragma unroll
    for (int i = 0; i < 2; i++)
        #pragma unroll
        for (int reg = 0; reg < 4; reg++) {
            const int grow = br0 + wr + 16*i + q4 + reg;
            #pragma unroll
            for (int j = 0; j < 2; j++) {
                const int c = wc + 16*j + m;
                AB[(size_t)grow * 512 + ct*64 + c] = acc[i][j][reg] + bcab[ct*64 + c];
            }
        }
}

// ---------------------------------------------------------------------------
// K6: D[b,n,m] = SQ[n] + SQ[m] - 2 (h_n . h_m)
// ---------------------------------------------------------------------------
__global__ __launch_bounds__(256) void k_dist_m(
    const ushort* __restrict__ Hh, const ushort* __restrict__ Hl,
    const float* __restrict__ SQ, float* __restrict__ D)
{
    const int b = blockIdx.z;
    const int m0 = blockIdx.x * 64, n0 = blockIdx.y * 64;

    MM64_PROLOGUE();

    for (int k0 = 0; k0 < HID; k0 += BK) {
        stage_u(Ah, Hh + (size_t)(b*NN + n0) * 128 + k0, 128, tid);
        stage_u(Al, Hl + (size_t)(b*NN + n0) * 128 + k0, 128, tid);
        stage_u(Bh, Hh + (size_t)(b*NN + m0) * 128 + k0, 128, tid);
        stage_u(Bl, Hl + (size_t)(b*NN + m0) * 128 + k0, 128, tid);
        __syncthreads();
        mma_step64(Ah, Al, Bh, Bl, acc, wr, wc, lane);
        __syncthreads();
    }

    const int gb = b * NN;
    float* Db = D + (size_t)b * NN * NN;
    const int m = lane & 15, q4 = (lane >> 4) * 4;
    float sqm[2];
    #pragma unroll
    for (int j = 0; j < 2; j++) sqm[j] = SQ[gb + m0 + wc + 16*j + m];
    #pragma unroll
    for (int i = 0; i < 2; i++)
        #pragma unroll
        for (int reg = 0; reg < 4; reg++) {
            const int n = n0 + wr + 16*i + q4 + reg;
            const float sqn = SQ[gb + n];
            #pragma unroll
            for (int j = 0; j < 2; j++)
                Db[(size_t)n * NN + m0 + wc + 16*j + m]
                    = sqn + sqm[j] - 2.0f * acc[i][j][reg];
        }
}

// ---------------------------------------------------------------------------
// K7: per-row top-16 + gather-max + LayerNorm + SELU (wave per row)
// ---------------------------------------------------------------------------
__global__ __launch_bounds__(256) void k_out(
    const float* __restrict__ D, const float* __restrict__ AB,
    const float* __restrict__ ln_scale, const float* __restrict__ ln_bias,
    float* __restrict__ out)
{
    const int row  = blockIdx.x * 4 + (threadIdx.x >> 6);
    const int lane = threadIdx.x & 63;
    const int gb0  = row & ~(NN - 1);

    const float* drow = D + (size_t)row * NN;
    const float4 q0 = ((const float4*)drow)[lane];
    const float4 q1 = ((const float4*)drow)[64 + lane];
    float v[8] = {q0.x, q0.y, q0.z, q0.w, q1.x, q1.y, q1.z, q1.w};

    const float lsc0 = ln_scale[lane],       lbi0 = ln_bias[lane];
    const float lsc1 = ln_scale[lane + 64],  lbi1 = ln_bias[lane + 64];
    const float lsc2 = ln_scale[lane + 128], lbi2 = ln_bias[lane + 128];
    const float lsc3 = ln_scale[lane + 192], lbi3 = ln_bias[lane + 192];
    const float* arow = AB + (size_t)row * 512;
    const float a0 = arow[lane], a1 = arow[lane + 64],
                a2 = arow[lane + 128], a3 = arow[lane + 192];

    float bm0 = -INFINITY, bm1 = -INFINITY, bm2 = -INFINITY, bm3 = -INFINITY;

    for (int it = 0; it < TOPK; it++) {
        float bestv = v[0]; int bestm = 4*lane;
        #pragma unroll
        for (int j = 1; j < 8; j++) {
            const int m = (j >> 2)*256 + 4*lane + (j & 3);
            if (v[j] < bestv) { bestv = v[j]; bestm = m; }
        }
        #pragma unroll
        for (int off = 1; off < 64; off <<= 1) {
            const float ov = __shfl_xor(bestv, off);
            const int   om = __shfl_xor(bestm, off);
            if (ov < bestv || (ov == bestv && om < bestm)) { bestv = ov; bestm = om; }
        }
        const float* brow = AB + (size_t)(gb0 + bestm) * 512 + 256;
        bm0 = fmaxf(bm0, brow[lane]);
        bm1 = fmaxf(bm1, brow[lane + 64]);
        bm2 = fmaxf(bm2, brow[lane + 128]);
        bm3 = fmaxf(bm3, brow[lane + 192]);
        if (((bestm >> 2) & 63) == lane) {
            const int jj = ((bestm >> 8) << 2) | (bestm & 3);
            #pragma unroll
            for (int j = 0; j < 8; j++) if (j == jj) v[j] = INFINITY;
        }
    }

    float y0 = a0 + bm0, y1 = a1 + bm1, y2 = a2 + bm2, y3 = a3 + bm3;

    float s = y0 + y1 + y2 + y3;
    #pragma unroll
    for (int off = 1; off < 64; off <<= 1) s += __shfl_xor(s, off);
    const float mu = s * (1.0f/256.0f);
    const float d0 = y0 - mu, d1 = y1 - mu, d2 = y2 - mu, d3 = y3 - mu;
    float s2 = d0*d0 + d1*d1 + d2*d2 + d3*d3;
    #pragma unroll
    for (int off = 1; off < 64; off <<= 1) s2 += __shfl_xor(s2, off);
    const float var = s2 * (1.0f/256.0f);
    const float rstd = rsqrtf(var + LN_EPS);

    const float lam = 1.0507009873554805f, alpha = 1.6732632423543772f;
    float* orow = out + (size_t)row * FOUT;
    { const float z = d0*rstd*lsc0 + lbi0; orow[lane]       = z > 0.f ? lam*z : lam*alpha*expm1f(z); }
    { const float z = d1*rstd*lsc1 + lbi1; orow[lane + 64]  = z > 0.f ? lam*z : lam*alpha*expm1f(z); }
    { const float z = d2*rstd*lsc2 + lbi2; orow[lane + 128] = z > 0.f ? lam*z : lam*alpha*expm1f(z); }
    { const float z = d3*rstd*lsc3 + lbi3; orow[lane + 192] = z > 0.f ? lam*z : lam*alpha*expm1f(z); }
}

// ---------------------------------------------------------------------------
extern "C" void kernel_launch(void* const* d_in, const int* in_sizes, int n_in,
                              void* d_out, int out_size, void* d_ws, size_t ws_size,
                              hipStream_t stream)
{
    (void)in_sizes; (void)n_in; (void)out_size; (void)ws_size;
    const float* X   = (const float*)d_in[0];
    const float* Wq  = (const float*)d_in[2];
    const float* bq  = (const float*)d_in[3];
    const float* Wk  = (const float*)d_in[4];
    const float* bk  = (const float*)d_in[5];
    const float* Wv  = (const float*)d_in[6];
    const float* bv  = (const float*)d_in[7];
    const float* Wr  = (const float*)d_in[8];
    const float* br  = (const float*)d_in[9];
    const float* Wc  = (const float*)d_in[10];
    const float* bc  = (const float*)d_in[11];
    const float* lns = (const float*)d_in[12];
    const float* lnb = (const float*)d_in[13];
    float* out = (float*)d_out;

    char* cur = (char*)d_ws;
    auto alloc = [&](size_t bytes) { char* p = cur; cur += (bytes + 255) & ~size_t(255); return p; };

    float*  S    = (float*)alloc((size_t)NB*NN*NN*4);     // scores, then D
    float*  AB   = (float*)alloc((size_t)ROWS*512*4);
    float*  Rbuf = (float*)alloc((size_t)ROWS*128*4);
    float*  SQ   = (float*)alloc((size_t)ROWS*4);
    float*  bcat = (float*)alloc(512*4);
    float*  bcab = (float*)alloc(512*4);
    ushort* Xh   = (ushort*)alloc((size_t)ROWS*256*2);
    ushort* Xl   = (ushort*)alloc((size_t)ROWS*256*2);
    ushort* Yh   = (ushort*)alloc((size_t)ROWS*256*2);    // q|k planes
    ushort* Yl   = (ushort*)alloc((size_t)ROWS*256*2);
    ushort* Vth  = (ushort*)alloc((size_t)NB*128*512*2);
    ushort* Vtl  = (ushort*)alloc((size_t)NB*128*512*2);
    ushort* Ph   = (ushort*)alloc((size_t)ROWS*512*2);
    ushort* Pl   = (ushort*)alloc((size_t)ROWS*512*2);
    ushort* Hh   = (ushort*)alloc((size_t)ROWS*128*2);
    ushort* Hl   = (ushort*)alloc((size_t)ROWS*128*2);
    ushort* Wth  = (ushort*)alloc((size_t)512*256*2);
    ushort* Wtl  = (ushort*)alloc((size_t)512*256*2);
    ushort* Wcth = (ushort*)alloc((size_t)512*128*2);
    ushort* Wctl = (ushort*)alloc((size_t)512*128*2);
    float*  D    = S;

    k_prep_w  <<<17,           256, 0, stream>>>(Wq,Wk,Wv,Wr,Wc, bq,bk,bv,br,bc,
                                                 Wth,Wtl,Wcth,Wctl, bcat,bcab, SQ);
    k_prep_x  <<<ROWS*256/(256*8), 256, 0, stream>>>(X, Xh, Xl);
    k_proj_m  <<<dim3(8,128),  256, 0, stream>>>(Xh,Xl, Wth,Wtl, bcat, Yh,Yl, Vth,Vtl, Rbuf);
    k_scores_m<<<dim3(8,8,16), 256, 0, stream>>>(Yh,Yl, S);
    k_softmax2<<<ROWS,         256, 0, stream>>>(S, Ph, Pl);
    k_hgemm_m <<<dim3(2,8,16), 256, 0, stream>>>(Ph,Pl, Vth,Vtl, Rbuf, Hh,Hl, SQ);
    k_ab_m    <<<dim3(8,128),  256, 0, stream>>>(Hh,Hl, Wcth,Wctl, bcab, AB);
    k_dist_m  <<<dim3(8,8,16), 256, 0, stream>>>(Hh,Hl, SQ, D);
    k_out     <<<ROWS/4,       256, 0, stream>>>(D, AB, lns, lnb, out);
}